// Round 2
// baseline (1825.695 us; speedup 1.0000x reference)
//
#include <hip/hip_runtime.h>
#include <cmath>

typedef unsigned short u16;
typedef __bf16 bf16x8 __attribute__((ext_vector_type(8)));
typedef float f32x4 __attribute__((ext_vector_type(4)));
typedef u16 u16x4 __attribute__((ext_vector_type(4)));

#define GLOAD16(g, l) __builtin_amdgcn_global_load_lds( \
    (const __attribute__((address_space(1))) unsigned int*)(g), \
    (__attribute__((address_space(3))) unsigned int*)(l), 16, 0, 0)

__device__ __forceinline__ u16 f2b(float f) {
  unsigned u = __builtin_bit_cast(unsigned, f);
  unsigned r = (u + 0x7fffu + ((u >> 16) & 1u)) >> 16;
  return (u16)r;
}

// ---------------- transpose + f32->bf16 convert:  W[K][N] f32 -> Wt[N][Kp] bf16 (zero-pad K..Kp)
__global__ __launch_bounds__(256)
void transw_k(const float* __restrict__ W, u16* __restrict__ Wt,
              int K, int N, int Kp, long sIn, long sOut)
{
  __shared__ float t[32][33];
  int n0 = blockIdx.x * 32, k0 = blockIdx.y * 32, l = blockIdx.z;
  const float* Wl = W + (long)l * sIn;
  u16* Wo = Wt + (long)l * sOut;
  int tx = threadIdx.x & 31, ty = threadIdx.x >> 5;
  #pragma unroll
  for (int i = 0; i < 4; ++i) {
    int k = k0 + ty + i * 8;
    t[ty + i * 8][tx] = (k < K) ? Wl[(long)k * N + n0 + tx] : 0.0f;
  }
  __syncthreads();
  #pragma unroll
  for (int i = 0; i < 4; ++i) {
    int n = n0 + ty + i * 8;
    Wo[(long)n * Kp + k0 + tx] = f2b(t[tx][ty + i * 8]);
  }
}

// ---------------- concat qkv biases: out[12][2304]
__global__ void biascat_k(const float* bq0, const float* bk0, const float* bv0,
                          const float* bq1, const float* bk1, const float* bv1, float* o)
{
  int idx = blockIdx.x * 256 + threadIdx.x;            // 12*2304
  int c = idx % 2304, l = idx / 2304;
  int st = l / 6, li = l % 6;
  const float* src = (c < 768) ? (st ? bq1 : bq0) : (c < 1536) ? (st ? bk1 : bk0) : (st ? bv1 : bv0);
  o[idx] = src[li * 768 + (c % 768)];
}

// ---------------- cond f32 [512][438] -> bf16 [512][448] zero-padded
__global__ void condcvt_k(const float* __restrict__ c, u16* __restrict__ o)
{
  int idx = blockIdx.x * 256 + threadIdx.x;            // 512*448
  int k = idx % 448, r = idx / 448;
  o[idx] = f2b(k < 438 ? c[r * 438 + k] : 0.0f);
}

// ---------------- token embeddings + pos_emb for streams 1,2 -> x f32
__global__ void embed_k(const int* __restrict__ iu, const int* __restrict__ idn,
                        const float* __restrict__ teu, const float* __restrict__ ted,
                        const float* __restrict__ pe, float* __restrict__ x)
{
  int idx = blockIdx.x * 256 + threadIdx.x;            // 2*512*192
  int c4 = idx % 192; int rest = idx / 192;
  int tt = rest % 512; int b = rest / 512;
  int i = tt & 255; int s = tt >> 8;
  int tok = s ? idn[b * 256 + i] : iu[b * 256 + i];
  const float4* src = (const float4*)(s ? (ted + (long)tok * 768) : (teu + (long)tok * 768));
  int prow = 256 + s * 256 + i;
  float4 pv = ((const float4*)(pe + (long)prow * 768))[c4];
  float4 sv = src[c4];
  float4 ov; ov.x = sv.x + pv.x; ov.y = sv.y + pv.y; ov.z = sv.z + pv.z; ov.w = sv.w + pv.w;
  ((float4*)(x + ((long)b * 768 + prow) * 768))[c4] = ov;
}

// ---------------- LayerNorm f32 in -> bf16 out, C=768, wave per row
__global__ __launch_bounds__(256)
void ln_k(const float* __restrict__ x, const float* __restrict__ gg,
          const float* __restrict__ bb, u16* __restrict__ out)
{
  int row = blockIdx.x * 4 + (threadIdx.x >> 6);
  int lane = threadIdx.x & 63;
  const float* xr = x + (long)row * 768;
  float v[12]; float s = 0.0f;
  #pragma unroll
  for (int j = 0; j < 12; ++j) { v[j] = xr[lane + 64 * j]; s += v[j]; }
  #pragma unroll
  for (int d = 1; d < 64; d <<= 1) s += __shfl_xor(s, d);
  float mean = s * (1.0f / 768.0f);
  float s2 = 0.0f;
  #pragma unroll
  for (int j = 0; j < 12; ++j) { float d = v[j] - mean; s2 += d * d; }
  #pragma unroll
  for (int d = 1; d < 64; d <<= 1) s2 += __shfl_xor(s2, d);
  float rstd = rsqrtf(s2 * (1.0f / 768.0f) + 1e-5f);
  u16* orow = out + (long)row * 768;
  #pragma unroll
  for (int j = 0; j < 12; ++j) {
    int c = lane + 64 * j;
    orow[c] = f2b((v[j] - mean) * rstd * gg[c] + bb[c]);
  }
}

// ---------------- GEMM: C[M,N] = A[M,K](bf16) @ Bt[N,K](bf16)^T, 64x64 tile, BK=64
// ring-3 LDS buffers, depth-2 prefetch, counted vmcnt, single raw barrier per K-step
#define EPI_PLAIN 0
#define EPI_PE    1
#define EPI_QKV   2
#define EPI_RES   3
#define EPI_GELU  4

template<int EPI, bool BIAS>
__global__ __launch_bounds__(256)
void gemm_k(const u16* __restrict__ A, const u16* __restrict__ Bt, const float* __restrict__ bias,
            float* outf, u16* outb, u16* qb, u16* kb, u16* vT, const float* aux,
            int M, int N, int K, int lda, int ldc,
            int astr, int aoff, int cstr, int coff)
{
  __shared__ alignas(16) u16 Al[3 * 4096];
  __shared__ alignas(16) u16 Bl[3 * 4096];
  const int tid = threadIdx.x;
  const int m0 = blockIdx.x * 64, n0 = blockIdx.y * 64;
  const int lane = tid & 63, w = tid >> 6, l15 = lane & 15, g = lane >> 4;
  const int wm = (w >> 1) * 32, wn = (w & 1) * 32;

  // staging: rows of 64 bf16 (128B, 8 slots of 16B); stored[row][s] = data[row][s^(row&7)]
  const int i0 = tid, i1 = tid + 256;
  const int r0 = i0 >> 3, r1 = i1 >> 3;
  const int s0i = ((i0 & 7) ^ (r0 & 7)) * 8, s1i = ((i1 & 7) ^ (r1 & 7)) * 8;
  const int am0 = m0 + r0, am1 = m0 + r1;
  const u16* ap0 = A + (long)((am0 >> 8) * astr + aoff + (am0 & 255)) * lda + s0i;
  const u16* ap1 = A + (long)((am1 >> 8) * astr + aoff + (am1 & 255)) * lda + s1i;
  const u16* bp0 = Bt + (long)(n0 + r0) * K + s0i;
  const u16* bp1 = Bt + (long)(n0 + r1) * K + s1i;
  const int ld0 = (i0 >> 6) * 512, ld1 = (i1 >> 6) * 512;

  const int ra0 = wm + l15, ra1 = ra0 + 16, rb0 = wn + l15, rb1 = rb0 + 16;
  int offA0[2], offA1[2], offB0[2], offB1[2];
  #pragma unroll
  for (int ks = 0; ks < 2; ++ks) {
    int so = 4 * ks + g;
    offA0[ks] = ra0 * 128 + ((so ^ (ra0 & 7)) << 4);
    offA1[ks] = ra1 * 128 + ((so ^ (ra1 & 7)) << 4);
    offB0[ks] = rb0 * 128 + ((so ^ (rb0 & 7)) << 4);
    offB1[ks] = rb1 * 128 + ((so ^ (rb1 & 7)) << 4);
  }

  f32x4 ac00{}, ac01{}, ac10{}, ac11{};

  auto STAGE = [&](int kt, int q) {
    u16* ab = Al + q * 4096; u16* bb = Bl + q * 4096;
    GLOAD16(ap0 + kt, ab + ld0);
    GLOAD16(ap1 + kt, ab + ld1);
    GLOAD16(bp0 + kt, bb + ld0);
    GLOAD16(bp1 + kt, bb + ld1);
  };
  auto COMPUTE = [&](int bbyte) {
    const char* Ab = (const char*)Al + bbyte;
    const char* Bb = (const char*)Bl + bbyte;
    #pragma unroll
    for (int ks = 0; ks < 2; ++ks) {
      bf16x8 a0 = *(const bf16x8*)(Ab + offA0[ks]);
      bf16x8 a1 = *(const bf16x8*)(Ab + offA1[ks]);
      bf16x8 b0 = *(const bf16x8*)(Bb + offB0[ks]);
      bf16x8 b1 = *(const bf16x8*)(Bb + offB1[ks]);
      ac00 = __builtin_amdgcn_mfma_f32_16x16x32_bf16(a0, b0, ac00, 0, 0, 0);
      ac01 = __builtin_amdgcn_mfma_f32_16x16x32_bf16(a0, b1, ac01, 0, 0, 0);
      ac10 = __builtin_amdgcn_mfma_f32_16x16x32_bf16(a1, b0, ac10, 0, 0, 0);
      ac11 = __builtin_amdgcn_mfma_f32_16x16x32_bf16(a1, b1, ac11, 0, 0, 0);
    }
  };

  const int nIter = K >> 6;
  STAGE(0, 0);
  if (nIter > 1) STAGE(64, 1);
  int cur = 0;
  for (int t = 0; t < nIter - 1; ++t) {
    asm volatile("s_waitcnt vmcnt(4)" ::: "memory");
    __builtin_amdgcn_s_barrier();
    int nb = t + 2;
    if (nb < nIter) STAGE(nb << 6, nb == 2 ? 2 : (cur == 0 ? 2 : cur - 1));
    COMPUTE(cur * 8192);
    cur = (cur == 2) ? 0 : cur + 1;
  }
  asm volatile("s_waitcnt vmcnt(0)" ::: "memory");
  __builtin_amdgcn_s_barrier();
  COMPUTE(cur * 8192);

  #pragma unroll
  for (int mi = 0; mi < 2; ++mi)
  #pragma unroll
  for (int ni = 0; ni < 2; ++ni) {
    f32x4 a = (mi == 0) ? ((ni == 0) ? ac00 : ac01) : ((ni == 0) ? ac10 : ac11);
    int col = n0 + wn + 16 * ni + l15;
    float bv = BIAS ? bias[col] : 0.0f;
    int mlb = m0 + wm + 16 * mi + 4 * g;   // row of r=0 (D row = 4*(lane>>4)+r)
    if (EPI == EPI_QKV) {
      if (col >= 1536) {
        int c2 = col - 1536, hh = c2 >> 6, dd = c2 & 63;
        int bb2 = mlb >= 768 ? 1 : 0;
        int t0 = mlb - bb2 * 768;
        u16x4 pk;
        #pragma unroll
        for (int r = 0; r < 4; ++r) pk[r] = f2b(a[r] + bv);
        *(u16x4*)(vT + (long)((bb2 * 12 + hh) * 64 + dd) * 768 + t0) = pk;
      } else {
        u16* dst = (col < 768) ? (qb + (long)mlb * 768 + col) : (kb + (long)mlb * 768 + (col - 768));
        #pragma unroll
        for (int r = 0; r < 4; ++r) dst[(long)r * 768] = f2b(a[r] + bv);
      }
    } else {
      #pragma unroll
      for (int r = 0; r < 4; ++r) {
        int rg = mlb + r;
        long crow = (long)(rg >> 8) * cstr + coff + (rg & 255);
        float v = a[r] + bv;
        if (EPI == EPI_PLAIN)      outf[crow * ldc + col] = v;
        else if (EPI == EPI_PE)    outf[crow * ldc + col] = v + aux[(long)(rg & 255) * 768 + col];
        else if (EPI == EPI_RES)   outf[crow * ldc + col] = v + aux[crow * ldc + col];
        else if (EPI == EPI_GELU)  outb[crow * ldc + col] = f2b(0.5f * v * (1.0f + erff(v * 0.70710678f)));
      }
    }
  }
}

// ---------------- flash attention: 64 q-rows per WG, swapped QK^T, online softmax
// ring-3 K/V LDS buffers, depth-2 prefetch, counted vmcnt, 1 barrier per KV-tile
#define MFMA_BF16 __builtin_amdgcn_mfma_f32_16x16x32_bf16
__global__ __launch_bounds__(256)
void attn_k(const u16* __restrict__ qb, const u16* __restrict__ kb,
            const u16* __restrict__ vT, u16* __restrict__ y)
{
  __shared__ alignas(16) u16 Kl[3 * 4096];    // [key 64][d 64] swizzled, x3
  __shared__ alignas(16) u16 Vl[3 * 4096];    // [d 64][key 64] swizzled, x3
  __shared__ alignas(16) u16 Pl[4][16 * 72];  // per-wave P[q 16][key 64] pad 72
  const int qt = blockIdx.x, bh = blockIdx.y;
  const int b = bh / 12, h = bh - b * 12;
  const int tid = threadIdx.x, w = tid >> 6, lane = tid & 63, l15 = lane & 15, g = lane >> 4;
  const int qrow = qt * 64 + w * 16 + l15;
  const int qm = qrow & 255;
  const u16* qp = qb + (long)(b * 768 + qrow) * 768 + h * 64;
  bf16x8 qf0 = *(const bf16x8*)(qp + 8 * g);
  bf16x8 qf1 = *(const bf16x8*)(qp + 32 + 8 * g);
  f32x4 O0{}, O1{}, O2{}, O3{};
  float m_run = -1e30f, l_run = 0.0f;

  const int i0 = tid, i1 = tid + 256;
  const int kr0 = i0 >> 3, kr1 = i1 >> 3;
  const int sl0 = ((i0 & 7) ^ (kr0 & 7)) * 8, sl1 = ((i1 & 7) ^ (kr1 & 7)) * 8;
  const u16* kp0 = kb + (long)(b * 768 + kr0) * 768 + h * 64 + sl0;
  const u16* kp1 = kb + (long)(b * 768 + kr1) * 768 + h * 64 + sl1;
  const u16* vp0 = vT + (long)(bh * 64 + kr0) * 768 + sl0;
  const u16* vp1 = vT + (long)(bh * 64 + kr1) * 768 + sl1;
  const int ld0 = (i0 >> 6) * 512, ld1 = (i1 >> 6) * 512;

  auto STAGE = [&](int kt, int q) {
    u16* kbuf = Kl + q * 4096; u16* vbuf = Vl + q * 4096;
    GLOAD16(kp0 + (long)kt * 64 * 768, kbuf + ld0);
    GLOAD16(kp1 + (long)kt * 64 * 768, kbuf + ld1);
    GLOAD16(vp0 + kt * 64, vbuf + ld0);
    GLOAD16(vp1 + kt * 64, vbuf + ld1);
  };

  STAGE(0, 0);
  STAGE(1, 1);
  int cur = 0;
  for (int kt = 0; kt < 12; ++kt) {
    if (kt < 11) asm volatile("s_waitcnt vmcnt(4)" ::: "memory");
    else         asm volatile("s_waitcnt vmcnt(0)" ::: "memory");
    __builtin_amdgcn_s_barrier();
    int nb = kt + 2;
    if (nb < 12) STAGE(nb, nb == 2 ? 2 : (cur == 0 ? 2 : cur - 1));
    const char* Kb = (const char*)Kl + cur * 8192;
    const char* Vb = (const char*)Vl + cur * 8192;

    f32x4 s0{}, s1{}, s2{}, s3{};
    #pragma unroll
    for (int ks = 0; ks < 2; ++ks) {
      bf16x8 qf = ks ? qf1 : qf0;
      int sb = ((4 * ks + g) ^ (l15 & 7)) << 4;
      bf16x8 k0 = *(const bf16x8*)(Kb + (0  + l15) * 128 + sb);
      bf16x8 k1 = *(const bf16x8*)(Kb + (16 + l15) * 128 + sb);
      bf16x8 k2 = *(const bf16x8*)(Kb + (32 + l15) * 128 + sb);
      bf16x8 k3 = *(const bf16x8*)(Kb + (48 + l15) * 128 + sb);
      s0 = MFMA_BF16(k0, qf, s0, 0, 0, 0);
      s1 = MFMA_BF16(k1, qf, s1, 0, 0, 0);
      s2 = MFMA_BF16(k2, qf, s2, 0, 0, 0);
      s3 = MFMA_BF16(k3, qf, s3, 0, 0, 0);
    }
    float sv[16]; float tm = -1e30f;
    #pragma unroll
    for (int mt = 0; mt < 4; ++mt) {
      f32x4 sm4 = (mt == 0) ? s0 : (mt == 1) ? s1 : (mt == 2) ? s2 : s3;
      #pragma unroll
      for (int r = 0; r < 4; ++r) {
        int kg = kt * 64 + mt * 16 + 4 * g + r;
        float val = ((kg & 255) <= qm) ? sm4[r] * 0.125f : -1e30f;
        sv[mt * 4 + r] = val; tm = fmaxf(tm, val);
      }
    }
    tm = fmaxf(tm, __shfl_xor(tm, 16));
    tm = fmaxf(tm, __shfl_xor(tm, 32));
    float mn = fmaxf(m_run, tm);
    float alpha = __expf(m_run - mn);
    float ps = 0.0f; u16 pb16[16];
    #pragma unroll
    for (int j = 0; j < 16; ++j) {
      float p = (sv[j] <= -1e29f) ? 0.0f : __expf(sv[j] - mn);
      ps += p; pb16[j] = f2b(p);
    }
    ps += __shfl_xor(ps, 16); ps += __shfl_xor(ps, 32);
    l_run = l_run * alpha + ps; m_run = mn;
    // broadcast alpha for rows 4g..4g+3 via shfl (alpha is uniform per l15 across g-groups)
    float a0 = __shfl(alpha, 4 * g + 0);
    float a1 = __shfl(alpha, 4 * g + 1);
    float a2 = __shfl(alpha, 4 * g + 2);
    float a3 = __shfl(alpha, 4 * g + 3);
    #pragma unroll
    for (int mt = 0; mt < 4; ++mt) {
      u16x4 pk; pk[0] = pb16[4*mt]; pk[1] = pb16[4*mt+1]; pk[2] = pb16[4*mt+2]; pk[3] = pb16[4*mt+3];
      *(u16x4*)((char*)&Pl[w][0] + l15 * 144 + mt * 32 + 8 * g) = pk;
    }
    O0[0] *= a0; O0[1] *= a1; O0[2] *= a2; O0[3] *= a3;
    O1[0] *= a0; O1[1] *= a1; O1[2] *= a2; O1[3] *= a3;
    O2[0] *= a0; O2[1] *= a1; O2[2] *= a2; O2[3] *= a3;
    O3[0] *= a0; O3[1] *= a1; O3[2] *= a2; O3[3] *= a3;
    asm volatile("s_waitcnt lgkmcnt(0)" ::: "memory");
    __builtin_amdgcn_sched_barrier(0);
    #pragma unroll
    for (int ks = 0; ks < 2; ++ks) {
      bf16x8 pf = *(const bf16x8*)((const char*)&Pl[w][0] + l15 * 144 + 64 * ks + 16 * g);
      int sb = ((4 * ks + g) ^ (l15 & 7)) << 4;
      bf16x8 v0 = *(const bf16x8*)(Vb + (0  + l15) * 128 + sb);
      bf16x8 v1 = *(const bf16x8*)(Vb + (16 + l15) * 128 + sb);
      bf16x8 v2 = *(const bf16x8*)(Vb + (32 + l15) * 128 + sb);
      bf16x8 v3 = *(const bf16x8*)(Vb + (48 + l15) * 128 + sb);
      O0 = MFMA_BF16(pf, v0, O0, 0, 0, 0);
      O1 = MFMA_BF16(pf, v1, O1, 0, 0, 0);
      O2 = MFMA_BF16(pf, v2, O2, 0, 0, 0);
      O3 = MFMA_BF16(pf, v3, O3, 0, 0, 0);
    }
    cur = (cur == 2) ? 0 : cur + 1;
  }
  float n0i = 1.0f / __shfl(l_run, 4 * g + 0);
  float n1i = 1.0f / __shfl(l_run, 4 * g + 1);
  float n2i = 1.0f / __shfl(l_run, 4 * g + 2);
  float n3i = 1.0f / __shfl(l_run, 4 * g + 3);
  long yr = (long)(b * 768 + qt * 64 + w * 16 + 4 * g);
  #pragma unroll
  for (int ni = 0; ni < 4; ++ni) {
    f32x4 Ov = (ni == 0) ? O0 : (ni == 1) ? O1 : (ni == 2) ? O2 : O3;
    int c = h * 64 + ni * 16 + l15;
    y[(yr + 0) * 768 + c] = f2b(Ov[0] * n0i);
    y[(yr + 1) * 768 + c] = f2b(Ov[1] * n1i);
    y[(yr + 2) * 768 + c] = f2b(Ov[2] * n2i);
    y[(yr + 3) * 768 + c] = f2b(Ov[3] * n3i);
  }
}

// ================= host =================
extern "C" void kernel_launch(void* const* d_in, const int* in_sizes, int n_in,
                              void* d_out, int out_size, void* d_ws, size_t ws_size,
                              hipStream_t stream)
{
  (void)in_sizes; (void)n_in; (void)out_size;
  auto F = [&](int i){ return (const float*)d_in[i]; };
  const int* idx_up = (const int*)d_in[0];
  const int* idx_dn = (const int*)d_in[1];
  const float* cond = F(2);
  const float* teu = F(3);
  const float* ted = F(4);
  const float* pe  = F(5);
  const float* cw  = F(6);
  const float* cb  = F(7);
  float* outp = (float*)d_out;
  char* ws = (char*)d_ws;

  size_t o = 0;
  auto take = [&](size_t bytes){ void* p = ws + o; o += bytes; return p; };
  float* x    = (float*)take(4718592);   // [1536][768] f32 residual stream
  u16*   h    = (u16*)take(2359296);     // LN out bf16
  u16*   qbuf = (u16*)take(2359296);
  u16*   kbuf = (u16*)take(2359296);
  u16*   vT   = (u16*)take(2359296);     // [24][64][768]
  u16*   y    = (u16*)take(2359296);
  u16*   fca  = (u16*)take(9437184);     // [1536][3072]
  u16*   xf   = (u16*)take(2359296);
  u16*   cbf  = (u16*)take(458752);      // cond bf16 [512][448]
  float* qkvb = (float*)take(110592);    // [12][2304]
  u16*   hut  = (u16*)take(786432);
  u16*   hdt  = (u16*)take(786432);
  u16*   cwt  = (u16*)take(688128);      // [768][448]
  const size_t WL = 14155776;            // per-layer transposed weights (bytes)
  bool up = (ws_size >= o + 12 * WL);
  size_t nsl = up ? 12 : 1;
  u16* qkvt = (u16*)(ws + o);
  u16* wot  = qkvt + nsl * 2304 * 768;
  u16* fct  = wot  + nsl * 768 * 768;
  u16* prt  = fct  + nsl * 3072 * 768;

  auto trans = [&](const float* src, u16* dst, int K, int N, int Kp, long sIn, long sOut, int nz){
    transw_k<<<dim3(N / 32, Kp / 32, nz), dim3(256), 0, stream>>>(src, dst, K, N, Kp, sIn, sOut);
  };

  if (up) {
    for (int s = 0; s < 2; ++s) {
      for (int p = 0; p < 3; ++p)
        trans(F(8 + 16*s + 2 + 2*p), qkvt + (size_t)s*6*2304*768 + (size_t)p*768*768,
              768, 768, 768, 768L*768, 2304L*768, 6);
      trans(F(8 + 16*s + 8),  wot + (size_t)s*6*768*768,  768, 768, 768, 768L*768, 768L*768, 6);
      trans(F(8 + 16*s + 12), fct + (size_t)s*6*3072*768, 768, 3072, 768, 768L*3072, 3072L*768, 6);
      trans(F(8 + 16*s + 14), prt + (size_t)s*6*768*3072, 3072, 768, 3072, 3072L*768, 768L*3072, 6);
    }
  }
  trans(F(42), hut, 768, 512, 768, 0, 0, 1);
  trans(F(43), hdt, 768, 512, 768, 0, 0, 1);
  trans(cw,    cwt, 438, 768, 448, 0, 0, 1);
  biascat_k<<<dim3(108), dim3(256), 0, stream>>>(F(11), F(13), F(15), F(27), F(29), F(31), qkvb);
  condcvt_k<<<dim3(896), dim3(256), 0, stream>>>(cond, cbf);
  embed_k<<<dim3(768), dim3(256), 0, stream>>>(idx_up, idx_dn, teu, ted, pe, x);
  // cond @ cond_w + cond_b + pos_emb -> x rows b*768 + (0..255)
  gemm_k<EPI_PE, true><<<dim3(8, 12), dim3(256), 0, stream>>>(cbf, cwt, cb,
      x, nullptr, nullptr, nullptr, nullptr, pe,
      512, 768, 448, 448, 768, 256, 0, 768, 0);

  for (int l = 0; l < 12; ++l) {
    int s = l / 6, li = l % 6;
    u16* qkvt_l = qkvt + (up ? (size_t)l : 0) * 2304 * 768;
    u16* wot_l  = wot  + (up ? (size_t)l : 0) * 768 * 768;
    u16* fct_l  = fct  + (up ? (size_t)l : 0) * 3072 * 768;
    u16* prt_l  = prt  + (up ? (size_t)l : 0) * 768 * 3072;
    if (!up) {
      for (int p = 0; p < 3; ++p)
        trans(F(8 + 16*s + 2 + 2*p) + (size_t)li*768*768, qkvt_l + (size_t)p*768*768, 768, 768, 768, 0, 0, 1);
      trans(F(8 + 16*s + 8)  + (size_t)li*768*768,  wot_l, 768, 768, 768, 0, 0, 1);
      trans(F(8 + 16*s + 12) + (size_t)li*768*3072, fct_l, 768, 3072, 768, 0, 0, 1);
      trans(F(8 + 16*s + 14) + (size_t)li*3072*768, prt_l, 3072, 768, 3072, 0, 0, 1);
    }
    ln_k<<<dim3(384), dim3(256), 0, stream>>>(x, F(8+16*s+0) + (size_t)li*768, F(8+16*s+1) + (size_t)li*768, h);
    gemm_k<EPI_QKV, true><<<dim3(24, 36), dim3(256), 0, stream>>>(h, qkvt_l, qkvb + (size_t)l*2304,
        nullptr, nullptr, qbuf, kbuf, vT, nullptr,
        1536, 2304, 768, 768, 768, 256, 0, 256, 0);
    attn_k<<<dim3(12, 24), dim3(256), 0, stream>>>(qbuf, kbuf, vT, y);
    gemm_k<EPI_RES, true><<<dim3(24, 12), dim3(256), 0, stream>>>(y, wot_l, F(8+16*s+9) + (size_t)li*768,
        x, nullptr, nullptr, nullptr, nullptr, x,
        1536, 768, 768, 768, 768, 256, 0, 256, 0);
    ln_k<<<dim3(384), dim3(256), 0, stream>>>(x, F(8+16*s+10) + (size_t)li*768, F(8+16*s+11) + (size_t)li*768, h);
    gemm_k<EPI_GELU, true><<<dim3(24, 48), dim3(256), 0, stream>>>(h, fct_l, F(8+16*s+13) + (size_t)li*3072,
        nullptr, fca, nullptr, nullptr, nullptr, nullptr,
        1536, 3072, 768, 768, 3072, 256, 0, 256, 0);
    gemm_k<EPI_RES, true><<<dim3(24, 12), dim3(256), 0, stream>>>(fca, prt_l, F(8+16*s+15) + (size_t)li*768,
        x, nullptr, nullptr, nullptr, nullptr, x,
        1536, 768, 3072, 3072, 768, 256, 0, 256, 0);
  }
  ln_k<<<dim3(384), dim3(256), 0, stream>>>(x, F(40), F(41), xf);
  gemm_k<EPI_PLAIN, false><<<dim3(8, 8), dim3(256), 0, stream>>>(xf, hut, nullptr,
      outp, nullptr, nullptr, nullptr, nullptr, nullptr,
      512, 512, 768, 768, 512, 768, 256, 256, 0);
  gemm_k<EPI_PLAIN, false><<<dim3(8, 8), dim3(256), 0, stream>>>(xf, hdt, nullptr,
      outp + 262144, nullptr, nullptr, nullptr, nullptr, nullptr,
      512, 512, 768, 768, 512, 768, 512, 256, 0);
}

// Round 3
// 1562.248 us; speedup vs baseline: 1.1686x; 1.1686x over previous
//
#include <hip/hip_runtime.h>
#include <cmath>

typedef unsigned short u16;
typedef __bf16 bf16x8 __attribute__((ext_vector_type(8)));
typedef float f32x4 __attribute__((ext_vector_type(4)));
typedef u16 u16x4 __attribute__((ext_vector_type(4)));
typedef u16 u16x2 __attribute__((ext_vector_type(2)));

#define GLOAD16(g, l) __builtin_amdgcn_global_load_lds( \
    (const __attribute__((address_space(1))) unsigned int*)(g), \
    (__attribute__((address_space(3))) unsigned int*)(l), 16, 0, 0)

__device__ __forceinline__ u16 f2b(float f) {
  unsigned u = __builtin_bit_cast(unsigned, f);
  unsigned r = (u + 0x7fffu + ((u >> 16) & 1u)) >> 16;
  return (u16)r;
}

// ---------------- transpose + f32->bf16 convert:  W[K][N] f32 -> Wt[N][Kp] bf16 (zero-pad K..Kp)
__global__ __launch_bounds__(256)
void transw_k(const float* __restrict__ W, u16* __restrict__ Wt,
              int K, int N, int Kp, long sIn, long sOut)
{
  __shared__ float t[32][33];
  int n0 = blockIdx.x * 32, k0 = blockIdx.y * 32, l = blockIdx.z;
  const float* Wl = W + (long)l * sIn;
  u16* Wo = Wt + (long)l * sOut;
  int tx = threadIdx.x & 31, ty = threadIdx.x >> 5;
  #pragma unroll
  for (int i = 0; i < 4; ++i) {
    int k = k0 + ty + i * 8;
    t[ty + i * 8][tx] = (k < K) ? Wl[(long)k * N + n0 + tx] : 0.0f;
  }
  __syncthreads();
  #pragma unroll
  for (int i = 0; i < 2; ++i) {
    int p = threadIdx.x + 256 * i;     // 0..511
    int nl = p >> 4, kk = (p & 15) * 2;
    u16x2 o2; o2[0] = f2b(t[kk][nl]); o2[1] = f2b(t[kk + 1][nl]);
    *(u16x2*)(Wo + (long)(n0 + nl) * Kp + k0 + kk) = o2;
  }
}

// ---------------- concat qkv biases: out[12][2304]
__global__ void biascat_k(const float* bq0, const float* bk0, const float* bv0,
                          const float* bq1, const float* bk1, const float* bv1, float* o)
{
  int idx = blockIdx.x * 256 + threadIdx.x;            // 12*2304
  int c = idx % 2304, l = idx / 2304;
  int st = l / 6, li = l % 6;
  const float* src = (c < 768) ? (st ? bq1 : bq0) : (c < 1536) ? (st ? bk1 : bk0) : (st ? bv1 : bv0);
  o[idx] = src[li * 768 + (c % 768)];
}

// ---------------- cond f32 [512][438] -> bf16 [512][448] zero-padded
__global__ void condcvt_k(const float* __restrict__ c, u16* __restrict__ o)
{
  int idx = blockIdx.x * 256 + threadIdx.x;            // 512*448
  int k = idx % 448, r = idx / 448;
  o[idx] = f2b(k < 438 ? c[r * 438 + k] : 0.0f);
}

// ---------------- token embeddings + pos_emb for streams 1,2 -> x f32
__global__ void embed_k(const int* __restrict__ iu, const int* __restrict__ idn,
                        const float* __restrict__ teu, const float* __restrict__ ted,
                        const float* __restrict__ pe, float* __restrict__ x)
{
  int idx = blockIdx.x * 256 + threadIdx.x;            // 2*512*192
  int c4 = idx % 192; int rest = idx / 192;
  int tt = rest % 512; int b = rest / 512;
  int i = tt & 255; int s = tt >> 8;
  int tok = s ? idn[b * 256 + i] : iu[b * 256 + i];
  const float4* src = (const float4*)(s ? (ted + (long)tok * 768) : (teu + (long)tok * 768));
  int prow = 256 + s * 256 + i;
  float4 pv = ((const float4*)(pe + (long)prow * 768))[c4];
  float4 sv = src[c4];
  float4 ov; ov.x = sv.x + pv.x; ov.y = sv.y + pv.y; ov.z = sv.z + pv.z; ov.w = sv.w + pv.w;
  ((float4*)(x + ((long)b * 768 + prow) * 768))[c4] = ov;
}

// ---------------- fused split-K reduce + residual + bias + LayerNorm
// x_new = xin + sum_{s<S} P[s] + bias; h = LN(x_new)*g+b; optionally write x_new
template<int S, bool WX>
__global__ __launch_bounds__(256)
void lnred_k(const float* __restrict__ xin, const float* __restrict__ P,
             const float* __restrict__ bias, const float* __restrict__ gg,
             const float* __restrict__ bb, float* __restrict__ xout,
             u16* __restrict__ h)
{
  int row = blockIdx.x * 4 + (threadIdx.x >> 6);
  int lane = threadIdx.x & 63;
  long base = (long)row * 768;
  float v[12]; float s = 0.0f;
  #pragma unroll
  for (int j = 0; j < 12; ++j) {
    int c = lane + 64 * j;
    float val = xin[base + c];
    if (S > 0) {
      val += bias[c];
      #pragma unroll
      for (int si = 0; si < S; ++si) val += P[(long)si * 1179648 + base + c];
    }
    if (WX) xout[base + c] = val;
    v[j] = val; s += val;
  }
  #pragma unroll
  for (int d = 1; d < 64; d <<= 1) s += __shfl_xor(s, d);
  float mean = s * (1.0f / 768.0f);
  float s2 = 0.0f;
  #pragma unroll
  for (int j = 0; j < 12; ++j) { float d = v[j] - mean; s2 += d * d; }
  #pragma unroll
  for (int d = 1; d < 64; d <<= 1) s2 += __shfl_xor(s2, d);
  float rstd = rsqrtf(s2 * (1.0f / 768.0f) + 1e-5f);
  u16* orow = h + base;
  #pragma unroll
  for (int j = 0; j < 12; ++j) {
    int c = lane + 64 * j;
    orow[c] = f2b((v[j] - mean) * rstd * gg[c] + bb[c]);
  }
}

// ---------------- heads reduce: out[2][512][512] = sum of 4 partial slabs each
__global__ __launch_bounds__(256)
void headred_k(const float* __restrict__ HP, float* __restrict__ out)
{
  int i4 = blockIdx.x * 256 + threadIdx.x;   // 131072 float4 groups
  int st = i4 >> 16, loc = i4 & 65535;
  const float4* basep = (const float4*)HP + (long)st * 4 * 65536 + loc;
  float4 a = basep[0], b = basep[65536], c = basep[2 * 65536], d = basep[3 * 65536];
  float4 r; r.x = a.x + b.x + c.x + d.x; r.y = a.y + b.y + c.y + d.y;
  r.z = a.z + b.z + c.z + d.z; r.w = a.w + b.w + c.w + d.w;
  ((float4*)out)[i4] = r;
}

// ---------------- GEMM: C[M,N] = A[M,K](bf16) @ Bt[N,K](bf16)^T, 64x64 tile, BK=64
// ring-2 LDS (32KB -> 5 blocks/CU), issue-then-vmcnt(4), 1 barrier/iter, split-K via blockIdx.z
#define EPI_PLAIN 0
#define EPI_PE    1
#define EPI_QKV   2
#define EPI_GELU  4
#define EPI_PART  5

template<int EPI, bool BIAS>
__global__ __launch_bounds__(256)
void gemm_k(const u16* __restrict__ A, const u16* __restrict__ Bt, const float* __restrict__ bias,
            float* outf, u16* outb, u16* qb, u16* kb, u16* vT, const float* aux,
            int M, int N, int Ks, int lda, int ldb, int ldc,
            int astr, int aoff, int cstr, int coff, int pstr)
{
  __shared__ alignas(16) u16 Al[2 * 4096];
  __shared__ alignas(16) u16 Bl[2 * 4096];
  const int tid = threadIdx.x;
  const int m0 = blockIdx.x * 64, n0 = blockIdx.y * 64;
  const int koff = blockIdx.z * Ks;
  const int lane = tid & 63, w = tid >> 6, l15 = lane & 15, g = lane >> 4;
  const int wm = (w >> 1) * 32, wn = (w & 1) * 32;

  // staging: rows of 64 bf16 (128B, 8 slots of 16B); stored[row][s] = data[row][s^(row&7)]
  const int i0 = tid, i1 = tid + 256;
  const int r0 = i0 >> 3, r1 = i1 >> 3;
  const int s0i = ((i0 & 7) ^ (r0 & 7)) * 8, s1i = ((i1 & 7) ^ (r1 & 7)) * 8;
  const int am0 = m0 + r0, am1 = m0 + r1;
  const u16* ap0 = A + (long)((am0 >> 8) * astr + aoff + (am0 & 255)) * lda + koff + s0i;
  const u16* ap1 = A + (long)((am1 >> 8) * astr + aoff + (am1 & 255)) * lda + koff + s1i;
  const u16* bp0 = Bt + (long)(n0 + r0) * ldb + koff + s0i;
  const u16* bp1 = Bt + (long)(n0 + r1) * ldb + koff + s1i;
  const int ld0 = (i0 >> 6) * 512, ld1 = (i1 >> 6) * 512;

  const int ra0 = wm + l15, ra1 = ra0 + 16, rb0 = wn + l15, rb1 = rb0 + 16;
  int offA0[2], offA1[2], offB0[2], offB1[2];
  #pragma unroll
  for (int ks = 0; ks < 2; ++ks) {
    int so = 4 * ks + g;
    offA0[ks] = ra0 * 128 + ((so ^ (ra0 & 7)) << 4);
    offA1[ks] = ra1 * 128 + ((so ^ (ra1 & 7)) << 4);
    offB0[ks] = rb0 * 128 + ((so ^ (rb0 & 7)) << 4);
    offB1[ks] = rb1 * 128 + ((so ^ (rb1 & 7)) << 4);
  }

  f32x4 ac00{}, ac01{}, ac10{}, ac11{};

  auto STAGE = [&](int kt, int q) {
    u16* ab = Al + q * 4096; u16* bb = Bl + q * 4096;
    GLOAD16(ap0 + kt, ab + ld0);
    GLOAD16(ap1 + kt, ab + ld1);
    GLOAD16(bp0 + kt, bb + ld0);
    GLOAD16(bp1 + kt, bb + ld1);
  };
  auto COMPUTE = [&](int bbyte) {
    const char* Ab = (const char*)Al + bbyte;
    const char* Bb = (const char*)Bl + bbyte;
    #pragma unroll
    for (int ks = 0; ks < 2; ++ks) {
      bf16x8 a0 = *(const bf16x8*)(Ab + offA0[ks]);
      bf16x8 a1 = *(const bf16x8*)(Ab + offA1[ks]);
      bf16x8 b0 = *(const bf16x8*)(Bb + offB0[ks]);
      bf16x8 b1 = *(const bf16x8*)(Bb + offB1[ks]);
      ac00 = __builtin_amdgcn_mfma_f32_16x16x32_bf16(a0, b0, ac00, 0, 0, 0);
      ac01 = __builtin_amdgcn_mfma_f32_16x16x32_bf16(a0, b1, ac01, 0, 0, 0);
      ac10 = __builtin_amdgcn_mfma_f32_16x16x32_bf16(a1, b0, ac10, 0, 0, 0);
      ac11 = __builtin_amdgcn_mfma_f32_16x16x32_bf16(a1, b1, ac11, 0, 0, 0);
    }
  };

  const int nIter = Ks >> 6;
  STAGE(0, 0);
  for (int t = 0; t < nIter; ++t) {
    __builtin_amdgcn_s_barrier();            // protects buf[(t+1)&1] (read at t-1)
    if (t + 1 < nIter) {
      STAGE((t + 1) << 6, (t + 1) & 1);
      asm volatile("s_waitcnt vmcnt(4)" ::: "memory");   // stage t landed
    } else {
      asm volatile("s_waitcnt vmcnt(0)" ::: "memory");
    }
    COMPUTE((t & 1) * 8192);
  }

  #pragma unroll
  for (int mi = 0; mi < 2; ++mi)
  #pragma unroll
  for (int ni = 0; ni < 2; ++ni) {
    f32x4 a = (mi == 0) ? ((ni == 0) ? ac00 : ac01) : ((ni == 0) ? ac10 : ac11);
    int col = n0 + wn + 16 * ni + l15;
    float bv = BIAS ? bias[col] : 0.0f;
    int mlb = m0 + wm + 16 * mi + 4 * g;   // row of r=0 (D row = 4*(lane>>4)+r)
    if (EPI == EPI_QKV) {
      if (col >= 1536) {
        int c2 = col - 1536, hh = c2 >> 6, dd = c2 & 63;
        int bb2 = mlb >= 768 ? 1 : 0;
        int t0 = mlb - bb2 * 768;
        u16x4 pk;
        #pragma unroll
        for (int r = 0; r < 4; ++r) pk[r] = f2b(a[r] + bv);
        *(u16x4*)(vT + (long)((bb2 * 12 + hh) * 64 + dd) * 768 + t0) = pk;
      } else {
        u16* dst = (col < 768) ? (qb + (long)mlb * 768 + col) : (kb + (long)mlb * 768 + (col - 768));
        #pragma unroll
        for (int r = 0; r < 4; ++r) dst[(long)r * 768] = f2b(a[r] + bv);
      }
    } else {
      #pragma unroll
      for (int r = 0; r < 4; ++r) {
        int rg = mlb + r;
        long crow = (long)(rg >> 8) * cstr + coff + (rg & 255);
        float v = a[r] + bv;
        if (EPI == EPI_PLAIN)      outf[crow * ldc + col] = v;
        else if (EPI == EPI_PE)    outf[crow * ldc + col] = v + aux[(long)(rg & 255) * 768 + col];
        else if (EPI == EPI_PART)  outf[(long)blockIdx.z * pstr + (long)rg * ldc + col] = v;
        else if (EPI == EPI_GELU)  outb[crow * ldc + col] = f2b(0.5f * v * (1.0f + erff(v * 0.70710678f)));
      }
    }
  }
}

// ---------------- flash attention: 32 q-rows / 2 waves per WG, masked-tile skipping
// ring-3 K/V LDS, depth-2 prefetch, counted vmcnt, 1 barrier per KV-tile
#define MFMA_BF16 __builtin_amdgcn_mfma_f32_16x16x32_bf16
__global__ __launch_bounds__(128)
void attn_k(const u16* __restrict__ qb, const u16* __restrict__ kb,
            const u16* __restrict__ vT, u16* __restrict__ y)
{
  __shared__ alignas(16) u16 Kl[3 * 4096];    // [key 64][d 64] swizzled, x3
  __shared__ alignas(16) u16 Vl[3 * 4096];    // [d 64][key 64] swizzled, x3
  __shared__ alignas(16) u16 Pl[2][16 * 72];  // per-wave P[q 16][key 64] pad 72
  const int qt = blockIdx.x, bh = blockIdx.y; // qt: 24 tiles of 32 q-rows
  const int b = bh / 12, h = bh - b * 12;
  const int tid = threadIdx.x, w = tid >> 6, lane = tid & 63, l15 = lane & 15, g = lane >> 4;
  const int qrow = qt * 32 + w * 16 + l15;
  const int qm = qrow & 255;
  const int q0 = (qt * 32) & 255;
  const unsigned nw4 = (q0 >> 6) + 1;         // live 64-key tiles per 256-stream
  const int niter = 3 * nw4;                  // 3,6,9,12
  const u16* qp = qb + (long)(b * 768 + qrow) * 768 + h * 64;
  bf16x8 qf0 = *(const bf16x8*)(qp + 8 * g);
  bf16x8 qf1 = *(const bf16x8*)(qp + 32 + 8 * g);
  f32x4 O0{}, O1{}, O2{}, O3{};
  float m_run = -1e30f, l_run = 0.0f;

  const u16* kp[4]; const u16* vp[4]; int ldsb[4];
  #pragma unroll
  for (int j = 0; j < 4; ++j) {
    int i = tid + 128 * j;
    int r = i >> 3, sl = ((i & 7) ^ (r & 7)) * 8;
    kp[j] = kb + (long)(b * 768 + r) * 768 + h * 64 + sl;
    vp[j] = vT + (long)(bh * 64 + r) * 768 + sl;
    ldsb[j] = (w + 2 * j) * 512;
  }

  auto STAGE = [&](int kt, int q) {
    u16* kd = Kl + q * 4096; u16* vd = Vl + q * 4096;
    #pragma unroll
    for (int j = 0; j < 4; ++j) GLOAD16(kp[j] + (long)kt * 64 * 768, kd + ldsb[j]);
    #pragma unroll
    for (int j = 0; j < 4; ++j) GLOAD16(vp[j] + kt * 64, vd + ldsb[j]);
  };
  auto MAP = [&](int it) {                     // it-th live tile -> kv-tile index
    unsigned sb = (unsigned)it / nw4;
    return (int)(sb * 4 + ((unsigned)it - sb * nw4));
  };

  STAGE(MAP(0), 0);
  STAGE(MAP(1), 1);
  int cur = 0;
  for (int it = 0; it < niter; ++it) {
    if (it < niter - 1) asm volatile("s_waitcnt vmcnt(8)" ::: "memory");
    else                asm volatile("s_waitcnt vmcnt(0)" ::: "memory");
    __builtin_amdgcn_s_barrier();
    if (it + 2 < niter) STAGE(MAP(it + 2), cur == 0 ? 2 : cur - 1);
    const int kt = MAP(it);
    const char* Kb = (const char*)Kl + cur * 8192;
    const char* Vb = (const char*)Vl + cur * 8192;

    f32x4 s0{}, s1{}, s2{}, s3{};
    #pragma unroll
    for (int ks = 0; ks < 2; ++ks) {
      bf16x8 qf = ks ? qf1 : qf0;
      int sb = ((4 * ks + g) ^ (l15 & 7)) << 4;
      bf16x8 k0 = *(const bf16x8*)(Kb + (0  + l15) * 128 + sb);
      bf16x8 k1 = *(const bf16x8*)(Kb + (16 + l15) * 128 + sb);
      bf16x8 k2 = *(const bf16x8*)(Kb + (32 + l15) * 128 + sb);
      bf16x8 k3 = *(const bf16x8*)(Kb + (48 + l15) * 128 + sb);
      s0 = MFMA_BF16(k0, qf, s0, 0, 0, 0);
      s1 = MFMA_BF16(k1, qf, s1, 0, 0, 0);
      s2 = MFMA_BF16(k2, qf, s2, 0, 0, 0);
      s3 = MFMA_BF16(k3, qf, s3, 0, 0, 0);
    }
    float sv[16]; float tm = -1e30f;
    #pragma unroll
    for (int mt = 0; mt < 4; ++mt) {
      f32x4 sm4 = (mt == 0) ? s0 : (mt == 1) ? s1 : (mt == 2) ? s2 : s3;
      #pragma unroll
      for (int r = 0; r < 4; ++r) {
        int kg = kt * 64 + mt * 16 + 4 * g + r;
        float val = ((kg & 255) <= qm) ? sm4[r] * 0.125f : -1e30f;
        sv[mt * 4 + r] = val; tm = fmaxf(tm, val);
      }
    }
    tm = fmaxf(tm, __shfl_xor(tm, 16));
    tm = fmaxf(tm, __shfl_xor(tm, 32));
    float mn = fmaxf(m_run, tm);
    float alpha = __expf(m_run - mn);
    float ps = 0.0f; u16 pb16[16];
    #pragma unroll
    for (int j = 0; j < 16; ++j) {
      float p = (sv[j] <= -1e29f) ? 0.0f : __expf(sv[j] - mn);
      ps += p; pb16[j] = f2b(p);
    }
    ps += __shfl_xor(ps, 16); ps += __shfl_xor(ps, 32);
    l_run = l_run * alpha + ps; m_run = mn;
    float a0 = __shfl(alpha, 4 * g + 0);
    float a1 = __shfl(alpha, 4 * g + 1);
    float a2 = __shfl(alpha, 4 * g + 2);
    float a3 = __shfl(alpha, 4 * g + 3);
    #pragma unroll
    for (int mt = 0; mt < 4; ++mt) {
      u16x4 pk; pk[0] = pb16[4*mt]; pk[1] = pb16[4*mt+1]; pk[2] = pb16[4*mt+2]; pk[3] = pb16[4*mt+3];
      *(u16x4*)((char*)&Pl[w][0] + l15 * 144 + mt * 32 + 8 * g) = pk;
    }
    O0[0] *= a0; O0[1] *= a1; O0[2] *= a2; O0[3] *= a3;
    O1[0] *= a0; O1[1] *= a1; O1[2] *= a2; O1[3] *= a3;
    O2[0] *= a0; O2[1] *= a1; O2[2] *= a2; O2[3] *= a3;
    O3[0] *= a0; O3[1] *= a1; O3[2] *= a2; O3[3] *= a3;
    asm volatile("s_waitcnt lgkmcnt(0)" ::: "memory");
    __builtin_amdgcn_sched_barrier(0);
    #pragma unroll
    for (int ks = 0; ks < 2; ++ks) {
      bf16x8 pf = *(const bf16x8*)((const char*)&Pl[w][0] + l15 * 144 + 64 * ks + 16 * g);
      int sb = ((4 * ks + g) ^ (l15 & 7)) << 4;
      bf16x8 v0 = *(const bf16x8*)(Vb + (0  + l15) * 128 + sb);
      bf16x8 v1 = *(const bf16x8*)(Vb + (16 + l15) * 128 + sb);
      bf16x8 v2 = *(const bf16x8*)(Vb + (32 + l15) * 128 + sb);
      bf16x8 v3 = *(const bf16x8*)(Vb + (48 + l15) * 128 + sb);
      O0 = MFMA_BF16(pf, v0, O0, 0, 0, 0);
      O1 = MFMA_BF16(pf, v1, O1, 0, 0, 0);
      O2 = MFMA_BF16(pf, v2, O2, 0, 0, 0);
      O3 = MFMA_BF16(pf, v3, O3, 0, 0, 0);
    }
    cur = (cur == 2) ? 0 : cur + 1;
  }
  float n0i = 1.0f / __shfl(l_run, 4 * g + 0);
  float n1i = 1.0f / __shfl(l_run, 4 * g + 1);
  float n2i = 1.0f / __shfl(l_run, 4 * g + 2);
  float n3i = 1.0f / __shfl(l_run, 4 * g + 3);
  long yr = (long)(b * 768 + qt * 32 + w * 16 + 4 * g);
  #pragma unroll
  for (int ni = 0; ni < 4; ++ni) {
    f32x4 Ov = (ni == 0) ? O0 : (ni == 1) ? O1 : (ni == 2) ? O2 : O3;
    int c = h * 64 + ni * 16 + l15;
    y[(yr + 0) * 768 + c] = f2b(Ov[0] * n0i);
    y[(yr + 1) * 768 + c] = f2b(Ov[1] * n1i);
    y[(yr + 2) * 768 + c] = f2b(Ov[2] * n2i);
    y[(yr + 3) * 768 + c] = f2b(Ov[3] * n3i);
  }
}

// ================= host =================
extern "C" void kernel_launch(void* const* d_in, const int* in_sizes, int n_in,
                              void* d_out, int out_size, void* d_ws, size_t ws_size,
                              hipStream_t stream)
{
  (void)in_sizes; (void)n_in; (void)out_size;
  auto F = [&](int i){ return (const float*)d_in[i]; };
  const int* idx_up = (const int*)d_in[0];
  const int* idx_dn = (const int*)d_in[1];
  const float* cond = F(2);
  const float* teu = F(3);
  const float* ted = F(4);
  const float* pe  = F(5);
  const float* cw  = F(6);
  const float* cb  = F(7);
  float* outp = (float*)d_out;
  char* ws = (char*)d_ws;

  size_t o = 0;
  auto take = [&](size_t bytes){ void* p = ws + o; o += bytes; return p; };
  float* x    = (float*)take(4718592);   // [1536][768] f32 residual stream
  u16*   h    = (u16*)take(2359296);     // LN out bf16
  u16*   qbuf = (u16*)take(2359296);
  u16*   kbuf = (u16*)take(2359296);
  u16*   vT   = (u16*)take(2359296);     // [24][64][768]
  u16*   y    = (u16*)take(2359296);
  u16*   fca  = (u16*)take(9437184);     // [1536][3072]
  u16*   xf   = (u16*)take(2359296);
  u16*   cbf  = (u16*)take(458752);      // cond bf16 [512][448]
  float* qkvb = (float*)take(110592);    // [12][2304]
  u16*   hut  = (u16*)take(786432);
  u16*   hdt  = (u16*)take(786432);
  u16*   cwt  = (u16*)take(688128);      // [768][448]
  float* P1   = (float*)take(9437184);   // proj partials  [2][1536][768]
  float* P2   = (float*)take(18874368);  // proj2 partials [4][1536][768]
  float* HP   = (float*)take(8388608);   // head partials  [2][4][512][512]
  const size_t WL = 14155776;            // per-layer transposed weights (bytes)
  bool up = (ws_size >= o + 12 * WL);
  size_t nsl = up ? 12 : 1;
  u16* qkvt = (u16*)(ws + o);
  u16* wot  = qkvt + nsl * 2304 * 768;
  u16* fct  = wot  + nsl * 768 * 768;
  u16* prt  = fct  + nsl * 3072 * 768;

  auto trans = [&](const float* src, u16* dst, int K, int N, int Kp, long sIn, long sOut, int nz){
    transw_k<<<dim3(N / 32, Kp / 32, nz), dim3(256), 0, stream>>>(src, dst, K, N, Kp, sIn, sOut);
  };

  if (up) {
    for (int s = 0; s < 2; ++s) {
      for (int p = 0; p < 3; ++p)
        trans(F(8 + 16*s + 2 + 2*p), qkvt + (size_t)s*6*2304*768 + (size_t)p*768*768,
              768, 768, 768, 768L*768, 2304L*768, 6);
      trans(F(8 + 16*s + 8),  wot + (size_t)s*6*768*768,  768, 768, 768, 768L*768, 768L*768, 6);
      trans(F(8 + 16*s + 12), fct + (size_t)s*6*3072*768, 768, 3072, 768, 768L*3072, 3072L*768, 6);
      trans(F(8 + 16*s + 14), prt + (size_t)s*6*768*3072, 3072, 768, 3072, 3072L*768, 768L*3072, 6);
    }
  }
  trans(F(42), hut, 768, 512, 768, 0, 0, 1);
  trans(F(43), hdt, 768, 512, 768, 0, 0, 1);
  trans(cw,    cwt, 438, 768, 448, 0, 0, 1);
  biascat_k<<<dim3(108), dim3(256), 0, stream>>>(F(11), F(13), F(15), F(27), F(29), F(31), qkvb);
  condcvt_k<<<dim3(896), dim3(256), 0, stream>>>(cond, cbf);
  embed_k<<<dim3(768), dim3(256), 0, stream>>>(idx_up, idx_dn, teu, ted, pe, x);
  // cond @ cond_w + cond_b + pos_emb -> x rows b*768 + (0..255)
  gemm_k<EPI_PE, true><<<dim3(8, 12, 1), dim3(256), 0, stream>>>(cbf, cwt, cb,
      x, nullptr, nullptr, nullptr, nullptr, pe,
      512, 768, 448, 448, 448, 768, 256, 0, 768, 0, 0);

  for (int l = 0; l < 12; ++l) {
    int s = l / 6, li = l % 6;
    u16* qkvt_l = qkvt + (up ? (size_t)l : 0) * 2304 * 768;
    u16* wot_l  = wot  + (up ? (size_t)l : 0) * 768 * 768;
    u16* fct_l  = fct  + (up ? (size_t)l : 0) * 3072 * 768;
    u16* prt_l  = prt  + (up ? (size_t)l : 0) * 768 * 3072;
    if (!up) {
      for (int p = 0; p < 3; ++p)
        trans(F(8 + 16*s + 2 + 2*p) + (size_t)li*768*768, qkvt_l + (size_t)p*768*768, 768, 768, 768, 0, 0, 1);
      trans(F(8 + 16*s + 8)  + (size_t)li*768*768,  wot_l, 768, 768, 768, 0, 0, 1);
      trans(F(8 + 16*s + 12) + (size_t)li*768*3072, fct_l, 768, 3072, 768, 0, 0, 1);
      trans(F(8 + 16*s + 14) + (size_t)li*3072*768, prt_l, 3072, 768, 3072, 0, 0, 1);
    }
    // LN1 (fused with previous layer's proj2 split-K reduce + residual)
    if (l == 0) {
      lnred_k<0, false><<<dim3(384), dim3(256), 0, stream>>>(x, nullptr, nullptr,
          F(8+16*s+0) + (size_t)li*768, F(8+16*s+1) + (size_t)li*768, nullptr, h);
    } else {
      int ps = (l - 1) / 6, pli = (l - 1) % 6;
      lnred_k<4, true><<<dim3(384), dim3(256), 0, stream>>>(x, P2,
          F(8+16*ps+15) + (size_t)pli*768,
          F(8+16*s+0) + (size_t)li*768, F(8+16*s+1) + (size_t)li*768, x, h);
    }
    gemm_k<EPI_QKV, true><<<dim3(24, 36, 1), dim3(256), 0, stream>>>(h, qkvt_l, qkvb + (size_t)l*2304,
        nullptr, nullptr, qbuf, kbuf, vT, nullptr,
        1536, 2304, 768, 768, 768, 768, 256, 0, 256, 0, 0);
    attn_k<<<dim3(24, 24), dim3(128), 0, stream>>>(qbuf, kbuf, vT, y);
    // attn out proj: split-K x2 -> P1
    gemm_k<EPI_PART, false><<<dim3(24, 12, 2), dim3(256), 0, stream>>>(y, wot_l, nullptr,
        P1, nullptr, nullptr, nullptr, nullptr, nullptr,
        1536, 768, 384, 768, 768, 768, 256, 0, 256, 0, 1179648);
    // LN2 fused with proj reduce + residual + bo
    lnred_k<2, true><<<dim3(384), dim3(256), 0, stream>>>(x, P1,
        F(8+16*s+9) + (size_t)li*768,
        F(8+16*s+10) + (size_t)li*768, F(8+16*s+11) + (size_t)li*768, x, h);
    gemm_k<EPI_GELU, true><<<dim3(24, 48, 1), dim3(256), 0, stream>>>(h, fct_l, F(8+16*s+13) + (size_t)li*3072,
        nullptr, fca, nullptr, nullptr, nullptr, nullptr,
        1536, 3072, 768, 768, 768, 3072, 256, 0, 256, 0, 0);
    // MLP out proj: split-K x4 -> P2 (reduced by next lnred / ln_f)
    gemm_k<EPI_PART, false><<<dim3(24, 12, 4), dim3(256), 0, stream>>>(fca, prt_l, nullptr,
        P2, nullptr, nullptr, nullptr, nullptr, nullptr,
        1536, 768, 768, 3072, 3072, 768, 256, 0, 256, 0, 1179648);
  }
  // ln_f fused with last proj2 reduce (x not needed afterwards)
  lnred_k<4, false><<<dim3(384), dim3(256), 0, stream>>>(x, P2,
      F(8+16*1+15) + (size_t)5*768, F(40), F(41), nullptr, xf);
  // heads: split-K x4 each, then fused reduce
  gemm_k<EPI_PART, false><<<dim3(8, 8, 4), dim3(256), 0, stream>>>(xf, hut, nullptr,
      HP, nullptr, nullptr, nullptr, nullptr, nullptr,
      512, 512, 192, 768, 768, 512, 768, 256, 256, 0, 262144);
  gemm_k<EPI_PART, false><<<dim3(8, 8, 4), dim3(256), 0, stream>>>(xf, hdt, nullptr,
      HP + 1048576, nullptr, nullptr, nullptr, nullptr, nullptr,
      512, 512, 192, 768, 768, 512, 768, 512, 256, 0, 262144);
  headred_k<<<dim3(512), dim3(256), 0, stream>>>(HP, outp);
}

// Round 4
// 1419.124 us; speedup vs baseline: 1.2865x; 1.1009x over previous
//
#include <hip/hip_runtime.h>
#include <cmath>

typedef unsigned short u16;
typedef __bf16 bf16x8 __attribute__((ext_vector_type(8)));
typedef float f32x4 __attribute__((ext_vector_type(4)));
typedef u16 u16x4 __attribute__((ext_vector_type(4)));
typedef u16 u16x2 __attribute__((ext_vector_type(2)));

#define GLOAD16(g, l) __builtin_amdgcn_global_load_lds( \
    (const __attribute__((address_space(1))) unsigned int*)(g), \
    (__attribute__((address_space(3))) unsigned int*)(l), 16, 0, 0)

__device__ __forceinline__ u16 f2b(float f) {
  unsigned u = __builtin_bit_cast(unsigned, f);
  unsigned r = (u + 0x7fffu + ((u >> 16) & 1u)) >> 16;
  return (u16)r;
}

// ---------------- transpose + f32->bf16 convert:  W[K][N] f32 -> Wt[N][Kp] bf16 (zero-pad K..Kp)
__global__ __launch_bounds__(256)
void transw_k(const float* __restrict__ W, u16* __restrict__ Wt,
              int K, int N, int Kp, long sIn, long sOut)
{
  __shared__ float t[32][33];
  int n0 = blockIdx.x * 32, k0 = blockIdx.y * 32, l = blockIdx.z;
  const float* Wl = W + (long)l * sIn;
  u16* Wo = Wt + (long)l * sOut;
  int tx = threadIdx.x & 31, ty = threadIdx.x >> 5;
  #pragma unroll
  for (int i = 0; i < 4; ++i) {
    int k = k0 + ty + i * 8;
    t[ty + i * 8][tx] = (k < K) ? Wl[(long)k * N + n0 + tx] : 0.0f;
  }
  __syncthreads();
  #pragma unroll
  for (int i = 0; i < 2; ++i) {
    int p = threadIdx.x + 256 * i;     // 0..511
    int nl = p >> 4, kk = (p & 15) * 2;
    u16x2 o2; o2[0] = f2b(t[kk][nl]); o2[1] = f2b(t[kk + 1][nl]);
    *(u16x2*)(Wo + (long)(n0 + nl) * Kp + k0 + kk) = o2;
  }
}

// ---------------- concat qkv biases: out[12][2304]
__global__ void biascat_k(const float* bq0, const float* bk0, const float* bv0,
                          const float* bq1, const float* bk1, const float* bv1, float* o)
{
  int idx = blockIdx.x * 256 + threadIdx.x;            // 12*2304
  int c = idx % 2304, l = idx / 2304;
  int st = l / 6, li = l % 6;
  const float* src = (c < 768) ? (st ? bq1 : bq0) : (c < 1536) ? (st ? bk1 : bk0) : (st ? bv1 : bv0);
  o[idx] = src[li * 768 + (c % 768)];
}

// ---------------- cond f32 [512][438] -> bf16 [512][448] zero-padded
__global__ void condcvt_k(const float* __restrict__ c, u16* __restrict__ o)
{
  int idx = blockIdx.x * 256 + threadIdx.x;            // 512*448
  int k = idx % 448, r = idx / 448;
  o[idx] = f2b(k < 438 ? c[r * 438 + k] : 0.0f);
}

// ---------------- token embeddings + pos_emb for streams 1,2 -> x f32
__global__ void embed_k(const int* __restrict__ iu, const int* __restrict__ idn,
                        const float* __restrict__ teu, const float* __restrict__ ted,
                        const float* __restrict__ pe, float* __restrict__ x)
{
  int idx = blockIdx.x * 256 + threadIdx.x;            // 2*512*192
  int c4 = idx % 192; int rest = idx / 192;
  int tt = rest % 512; int b = rest / 512;
  int i = tt & 255; int s = tt >> 8;
  int tok = s ? idn[b * 256 + i] : iu[b * 256 + i];
  const float4* src = (const float4*)(s ? (ted + (long)tok * 768) : (teu + (long)tok * 768));
  int prow = 256 + s * 256 + i;
  float4 pv = ((const float4*)(pe + (long)prow * 768))[c4];
  float4 sv = src[c4];
  float4 ov; ov.x = sv.x + pv.x; ov.y = sv.y + pv.y; ov.z = sv.z + pv.z; ov.w = sv.w + pv.w;
  ((float4*)(x + ((long)b * 768 + prow) * 768))[c4] = ov;
}

// ---------------- fused split-K reduce + residual + bias + LayerNorm
template<int S, bool WX>
__global__ __launch_bounds__(256)
void lnred_k(const float* __restrict__ xin, const float* __restrict__ P,
             const float* __restrict__ bias, const float* __restrict__ gg,
             const float* __restrict__ bb, float* __restrict__ xout,
             u16* __restrict__ h)
{
  int row = blockIdx.x * 4 + (threadIdx.x >> 6);
  int lane = threadIdx.x & 63;
  long base = (long)row * 768;
  float v[12]; float s = 0.0f;
  #pragma unroll
  for (int j = 0; j < 12; ++j) {
    int c = lane + 64 * j;
    float val = xin[base + c];
    if (S > 0) {
      val += bias[c];
      #pragma unroll
      for (int si = 0; si < S; ++si) val += P[(long)si * 1179648 + base + c];
    }
    if (WX) xout[base + c] = val;
    v[j] = val; s += val;
  }
  #pragma unroll
  for (int d = 1; d < 64; d <<= 1) s += __shfl_xor(s, d);
  float mean = s * (1.0f / 768.0f);
  float s2 = 0.0f;
  #pragma unroll
  for (int j = 0; j < 12; ++j) { float d = v[j] - mean; s2 += d * d; }
  #pragma unroll
  for (int d = 1; d < 64; d <<= 1) s2 += __shfl_xor(s2, d);
  float rstd = rsqrtf(s2 * (1.0f / 768.0f) + 1e-5f);
  u16* orow = h + base;
  #pragma unroll
  for (int j = 0; j < 12; ++j) {
    int c = lane + 64 * j;
    orow[c] = f2b((v[j] - mean) * rstd * gg[c] + bb[c]);
  }
}

// ---------------- heads reduce: out[2][512][512] = sum of 4 partial slabs each
__global__ __launch_bounds__(256)
void headred_k(const float* __restrict__ HP, float* __restrict__ out)
{
  int i4 = blockIdx.x * 256 + threadIdx.x;   // 131072 float4 groups
  int st = i4 >> 16, loc = i4 & 65535;
  const float4* basep = (const float4*)HP + (long)st * 4 * 65536 + loc;
  float4 a = basep[0], b = basep[65536], c = basep[2 * 65536], d = basep[3 * 65536];
  float4 r; r.x = a.x + b.x + c.x + d.x; r.y = a.y + b.y + c.y + d.y;
  r.z = a.z + b.z + c.z + d.z; r.w = a.w + b.w + c.w + d.w;
  ((float4*)out)[i4] = r;
}

// ---------------- GEMM: C[M,N] = A[M,K](bf16) @ Bt[N,K](bf16)^T
// templated tile: BM x BN block, WM x WN per wave (4x4 frags at 64x64), BK=64
// ring-2 LDS, SOUND schedule: own-vmcnt BEFORE barrier; counted vmcnt mid-loop
#define EPI_PLAIN 0
#define EPI_PE    1
#define EPI_QKV   2
#define EPI_GELU  4
#define EPI_PART  5

template<int BM, int BN, int WM, int WN, int EPI, bool BIAS>
__global__ __launch_bounds__(256)
void gemm_k(const u16* __restrict__ A, const u16* __restrict__ Bt, const float* __restrict__ bias,
            float* outf, u16* outb, u16* qb, u16* kb, u16* vT, const float* aux,
            int M, int N, int Ks, int lda, int ldb, int ldc,
            int astr, int aoff, int cstr, int coff, int pstr)
{
  constexpr int NWC = BN / WN;               // waves along N
  constexpr int NT  = (BM / WM) * NWC * 64;  // threads (=256 for all configs used)
  constexpr int LCH = (BM + BN) * 8;         // 16B chunks per buffer
  constexpr int LPT = LCH / NT;              // global_load_lds per thread per stage
  constexpr int MR = WM / 16, NR = WN / 16;
  __shared__ alignas(16) u16 Sl[2][(BM + BN) * 64];

  const int tid = threadIdx.x;
  const int m0 = blockIdx.x * BM, n0 = blockIdx.y * BN;
  const int koff = blockIdx.z * Ks;
  const int lane = tid & 63, w = tid >> 6, l15 = lane & 15, g = lane >> 4;
  const int wr = w / NWC, wc = w % NWC;

  // staging chunk c = tid + NT*j; chunk -> (region,row,slot); swizzled SOURCE, linear DEST
  const u16* gp[LPT]; int lbase[LPT];
  #pragma unroll
  for (int j = 0; j < LPT; ++j) {
    int c = tid + NT * j;
    int slot = c & 7;
    if (c < BM * 8) {
      int row = c >> 3;
      int se = (slot ^ (row & 7)) * 8;
      int am = m0 + row;
      gp[j] = A + (long)((am >> 8) * astr + aoff + (am & 255)) * lda + koff + se;
    } else {
      int rb = c - BM * 8;
      int row = rb >> 3;
      int se = (slot ^ (row & 7)) * 8;
      gp[j] = Bt + (long)(n0 + row) * ldb + koff + se;
    }
    lbase[j] = w * 512 + NT * 8 * j;         // wave-uniform LDS base (u16 elems)
  }

  // ds_read byte offsets: [ks][frag]
  int offA[2][MR], offB[2][NR];
  #pragma unroll
  for (int ks = 0; ks < 2; ++ks) {
    int s = 4 * ks + g;
    #pragma unroll
    for (int mi = 0; mi < MR; ++mi) {
      int r = wr * WM + mi * 16 + l15;
      offA[ks][mi] = r * 128 + ((s ^ (r & 7)) << 4);
    }
    #pragma unroll
    for (int ni = 0; ni < NR; ++ni) {
      int r = wc * WN + ni * 16 + l15;
      offB[ks][ni] = BM * 128 + r * 128 + ((s ^ (r & 7)) << 4);
    }
  }

  f32x4 acc[MR][NR];
  #pragma unroll
  for (int mi = 0; mi < MR; ++mi)
  #pragma unroll
  for (int ni = 0; ni < NR; ++ni) acc[mi][ni] = f32x4{};

  auto STAGE = [&](int kt, int buf) {
    #pragma unroll
    for (int j = 0; j < LPT; ++j) GLOAD16(gp[j] + kt, &Sl[buf][lbase[j]]);
  };
  auto COMPUTE = [&](int buf) {
    const char* Sb = (const char*)&Sl[buf][0];
    #pragma unroll
    for (int ks = 0; ks < 2; ++ks) {
      bf16x8 a[MR], b[NR];
      #pragma unroll
      for (int mi = 0; mi < MR; ++mi) a[mi] = *(const bf16x8*)(Sb + offA[ks][mi]);
      #pragma unroll
      for (int ni = 0; ni < NR; ++ni) b[ni] = *(const bf16x8*)(Sb + offB[ks][ni]);
      #pragma unroll
      for (int mi = 0; mi < MR; ++mi)
      #pragma unroll
      for (int ni = 0; ni < NR; ++ni)
        acc[mi][ni] = __builtin_amdgcn_mfma_f32_16x16x32_bf16(a[mi], b[ni], acc[mi][ni], 0, 0, 0);
    }
  };

  const int nIter = Ks >> 6;
  STAGE(0, 0);
  if (nIter > 1) STAGE(64, 1);
  for (int t = 0; t < nIter; ++t) {
    if (t + 1 < nIter) {
      if constexpr (LPT == 8) asm volatile("s_waitcnt vmcnt(8)" ::: "memory");
      else                    asm volatile("s_waitcnt vmcnt(4)" ::: "memory");
    } else {
      asm volatile("s_waitcnt vmcnt(0)" ::: "memory");
    }
    __builtin_amdgcn_s_barrier();            // all waves' stage-t landed
    COMPUTE(t & 1);
    if (t + 2 < nIter) {
      __builtin_amdgcn_s_barrier();          // all waves done reading buf[t&1]
      STAGE((t + 2) << 6, t & 1);
    }
  }

  #pragma unroll
  for (int mi = 0; mi < MR; ++mi)
  #pragma unroll
  for (int ni = 0; ni < NR; ++ni) {
    f32x4 a = acc[mi][ni];
    int col = n0 + wc * WN + ni * 16 + l15;
    float bv = BIAS ? bias[col] : 0.0f;
    int mlb = m0 + wr * WM + mi * 16 + 4 * g;
    if (EPI == EPI_QKV) {
      if (col >= 1536) {
        int c2 = col - 1536, hh = c2 >> 6, dd = c2 & 63;
        int bb2 = mlb >= 768 ? 1 : 0;
        int t0 = mlb - bb2 * 768;
        u16x4 pk;
        #pragma unroll
        for (int r = 0; r < 4; ++r) pk[r] = f2b(a[r] + bv);
        *(u16x4*)(vT + (long)((bb2 * 12 + hh) * 64 + dd) * 768 + t0) = pk;
      } else {
        u16* dst = (col < 768) ? (qb + (long)mlb * 768 + col) : (kb + (long)mlb * 768 + (col - 768));
        #pragma unroll
        for (int r = 0; r < 4; ++r) dst[(long)r * 768] = f2b(a[r] + bv);
      }
    } else {
      #pragma unroll
      for (int r = 0; r < 4; ++r) {
        int rg = mlb + r;
        long crow = (long)(rg >> 8) * cstr + coff + (rg & 255);
        float v = a[r] + bv;
        if (EPI == EPI_PLAIN)      outf[crow * ldc + col] = v;
        else if (EPI == EPI_PE)    outf[crow * ldc + col] = v + aux[(long)(rg & 255) * 768 + col];
        else if (EPI == EPI_PART)  outf[(long)blockIdx.z * pstr + (long)rg * ldc + col] = v;
        else if (EPI == EPI_GELU)  outb[crow * ldc + col] = f2b(0.5f * v * (1.0f + erff(v * 0.70710678f)));
      }
    }
  }
}

// ---------------- flash attention: 32 q-rows / 2 waves per WG, masked-tile skipping
#define MFMA_BF16 __builtin_amdgcn_mfma_f32_16x16x32_bf16
__global__ __launch_bounds__(128)
void attn_k(const u16* __restrict__ qb, const u16* __restrict__ kb,
            const u16* __restrict__ vT, u16* __restrict__ y)
{
  __shared__ alignas(16) u16 Kl[3 * 4096];
  __shared__ alignas(16) u16 Vl[3 * 4096];
  __shared__ alignas(16) u16 Pl[2][16 * 72];
  const int qt = blockIdx.x, bh = blockIdx.y;
  const int b = bh / 12, h = bh - b * 12;
  const int tid = threadIdx.x, w = tid >> 6, lane = tid & 63, l15 = lane & 15, g = lane >> 4;
  const int qrow = qt * 32 + w * 16 + l15;
  const int qm = qrow & 255;
  const int q0 = (qt * 32) & 255;
  const unsigned nw4 = (q0 >> 6) + 1;
  const int niter = 3 * nw4;
  const u16* qp = qb + (long)(b * 768 + qrow) * 768 + h * 64;
  bf16x8 qf0 = *(const bf16x8*)(qp + 8 * g);
  bf16x8 qf1 = *(const bf16x8*)(qp + 32 + 8 * g);
  f32x4 O0{}, O1{}, O2{}, O3{};
  float m_run = -1e30f, l_run = 0.0f;

  const u16* kp[4]; const u16* vp[4]; int ldsb[4];
  #pragma unroll
  for (int j = 0; j < 4; ++j) {
    int i = tid + 128 * j;
    int r = i >> 3, sl = ((i & 7) ^ (r & 7)) * 8;
    kp[j] = kb + (long)(b * 768 + r) * 768 + h * 64 + sl;
    vp[j] = vT + (long)(bh * 64 + r) * 768 + sl;
    ldsb[j] = (w + 2 * j) * 512;
  }

  auto STAGE = [&](int kt, int q) {
    u16* kd = Kl + q * 4096; u16* vd = Vl + q * 4096;
    #pragma unroll
    for (int j = 0; j < 4; ++j) GLOAD16(kp[j] + (long)kt * 64 * 768, kd + ldsb[j]);
    #pragma unroll
    for (int j = 0; j < 4; ++j) GLOAD16(vp[j] + kt * 64, vd + ldsb[j]);
  };
  auto MAP = [&](int it) {
    unsigned sb = (unsigned)it / nw4;
    return (int)(sb * 4 + ((unsigned)it - sb * nw4));
  };

  STAGE(MAP(0), 0);
  STAGE(MAP(1), 1);
  int cur = 0;
  for (int it = 0; it < niter; ++it) {
    if (it < niter - 1) asm volatile("s_waitcnt vmcnt(8)" ::: "memory");
    else                asm volatile("s_waitcnt vmcnt(0)" ::: "memory");
    __builtin_amdgcn_s_barrier();
    if (it + 2 < niter) STAGE(MAP(it + 2), cur == 0 ? 2 : cur - 1);
    const int kt = MAP(it);
    const char* Kb = (const char*)Kl + cur * 8192;
    const char* Vb = (const char*)Vl + cur * 8192;

    f32x4 s0{}, s1{}, s2{}, s3{};
    #pragma unroll
    for (int ks = 0; ks < 2; ++ks) {
      bf16x8 qf = ks ? qf1 : qf0;
      int sb = ((4 * ks + g) ^ (l15 & 7)) << 4;
      bf16x8 k0 = *(const bf16x8*)(Kb + (0  + l15) * 128 + sb);
      bf16x8 k1 = *(const bf16x8*)(Kb + (16 + l15) * 128 + sb);
      bf16x8 k2 = *(const bf16x8*)(Kb + (32 + l15) * 128 + sb);
      bf16x8 k3 = *(const bf16x8*)(Kb + (48 + l15) * 128 + sb);
      s0 = MFMA_BF16(k0, qf, s0, 0, 0, 0);
      s1 = MFMA_BF16(k1, qf, s1, 0, 0, 0);
      s2 = MFMA_BF16(k2, qf, s2, 0, 0, 0);
      s3 = MFMA_BF16(k3, qf, s3, 0, 0, 0);
    }
    float sv[16]; float tm = -1e30f;
    #pragma unroll
    for (int mt = 0; mt < 4; ++mt) {
      f32x4 sm4 = (mt == 0) ? s0 : (mt == 1) ? s1 : (mt == 2) ? s2 : s3;
      #pragma unroll
      for (int r = 0; r < 4; ++r) {
        int kg = kt * 64 + mt * 16 + 4 * g + r;
        float val = ((kg & 255) <= qm) ? sm4[r] * 0.125f : -1e30f;
        sv[mt * 4 + r] = val; tm = fmaxf(tm, val);
      }
    }
    tm = fmaxf(tm, __shfl_xor(tm, 16));
    tm = fmaxf(tm, __shfl_xor(tm, 32));
    float mn = fmaxf(m_run, tm);
    float alpha = __expf(m_run - mn);
    float ps = 0.0f; u16 pb16[16];
    #pragma unroll
    for (int j = 0; j < 16; ++j) {
      float p = (sv[j] <= -1e29f) ? 0.0f : __expf(sv[j] - mn);
      ps += p; pb16[j] = f2b(p);
    }
    ps += __shfl_xor(ps, 16); ps += __shfl_xor(ps, 32);
    l_run = l_run * alpha + ps; m_run = mn;
    float a0 = __shfl(alpha, 4 * g + 0);
    float a1 = __shfl(alpha, 4 * g + 1);
    float a2 = __shfl(alpha, 4 * g + 2);
    float a3 = __shfl(alpha, 4 * g + 3);
    #pragma unroll
    for (int mt = 0; mt < 4; ++mt) {
      u16x4 pk; pk[0] = pb16[4*mt]; pk[1] = pb16[4*mt+1]; pk[2] = pb16[4*mt+2]; pk[3] = pb16[4*mt+3];
      *(u16x4*)((char*)&Pl[w][0] + l15 * 144 + mt * 32 + 8 * g) = pk;
    }
    O0[0] *= a0; O0[1] *= a1; O0[2] *= a2; O0[3] *= a3;
    O1[0] *= a0; O1[1] *= a1; O1[2] *= a2; O1[3] *= a3;
    O2[0] *= a0; O2[1] *= a1; O2[2] *= a2; O2[3] *= a3;
    O3[0] *= a0; O3[1] *= a1; O3[2] *= a2; O3[3] *= a3;
    asm volatile("s_waitcnt lgkmcnt(0)" ::: "memory");
    __builtin_amdgcn_sched_barrier(0);
    #pragma unroll
    for (int ks = 0; ks < 2; ++ks) {
      bf16x8 pf = *(const bf16x8*)((const char*)&Pl[w][0] + l15 * 144 + 64 * ks + 16 * g);
      int sb = ((4 * ks + g) ^ (l15 & 7)) << 4;
      bf16x8 v0 = *(const bf16x8*)(Vb + (0  + l15) * 128 + sb);
      bf16x8 v1 = *(const bf16x8*)(Vb + (16 + l15) * 128 + sb);
      bf16x8 v2 = *(const bf16x8*)(Vb + (32 + l15) * 128 + sb);
      bf16x8 v3 = *(const bf16x8*)(Vb + (48 + l15) * 128 + sb);
      O0 = MFMA_BF16(pf, v0, O0, 0, 0, 0);
      O1 = MFMA_BF16(pf, v1, O1, 0, 0, 0);
      O2 = MFMA_BF16(pf, v2, O2, 0, 0, 0);
      O3 = MFMA_BF16(pf, v3, O3, 0, 0, 0);
    }
    cur = (cur == 2) ? 0 : cur + 1;
  }
  float n0i = 1.0f / __shfl(l_run, 4 * g + 0);
  float n1i = 1.0f / __shfl(l_run, 4 * g + 1);
  float n2i = 1.0f / __shfl(l_run, 4 * g + 2);
  float n3i = 1.0f / __shfl(l_run, 4 * g + 3);
  long yr = (long)(b * 768 + qt * 32 + w * 16 + 4 * g);
  #pragma unroll
  for (int ni = 0; ni < 4; ++ni) {
    f32x4 Ov = (ni == 0) ? O0 : (ni == 1) ? O1 : (ni == 2) ? O2 : O3;
    int c = h * 64 + ni * 16 + l15;
    y[(yr + 0) * 768 + c] = f2b(Ov[0] * n0i);
    y[(yr + 1) * 768 + c] = f2b(Ov[1] * n1i);
    y[(yr + 2) * 768 + c] = f2b(Ov[2] * n2i);
    y[(yr + 3) * 768 + c] = f2b(Ov[3] * n3i);
  }
}

// ================= host =================
extern "C" void kernel_launch(void* const* d_in, const int* in_sizes, int n_in,
                              void* d_out, int out_size, void* d_ws, size_t ws_size,
                              hipStream_t stream)
{
  (void)in_sizes; (void)n_in; (void)out_size;
  auto F = [&](int i){ return (const float*)d_in[i]; };
  const int* idx_up = (const int*)d_in[0];
  const int* idx_dn = (const int*)d_in[1];
  const float* cond = F(2);
  const float* teu = F(3);
  const float* ted = F(4);
  const float* pe  = F(5);
  const float* cw  = F(6);
  const float* cb  = F(7);
  float* outp = (float*)d_out;
  char* ws = (char*)d_ws;

  size_t o = 0;
  auto take = [&](size_t bytes){ void* p = ws + o; o += bytes; return p; };
  float* x    = (float*)take(4718592);   // [1536][768] f32 residual stream
  u16*   h    = (u16*)take(2359296);     // LN out bf16
  u16*   qbuf = (u16*)take(2359296);
  u16*   kbuf = (u16*)take(2359296);
  u16*   vT   = (u16*)take(2359296);     // [24][64][768]
  u16*   y    = (u16*)take(2359296);
  u16*   fca  = (u16*)take(9437184);     // [1536][3072]
  u16*   xf   = (u16*)take(2359296);
  u16*   cbf  = (u16*)take(458752);      // cond bf16 [512][448]
  float* qkvb = (float*)take(110592);    // [12][2304]
  u16*   hut  = (u16*)take(786432);
  u16*   hdt  = (u16*)take(786432);
  u16*   cwt  = (u16*)take(688128);      // [768][448]
  float* P1   = (float*)take(9437184);   // proj partials  [2][1536][768]
  float* P2   = (float*)take(18874368);  // proj2 partials [4][1536][768]
  float* HP   = (float*)take(8388608);   // head partials  [2][4][512][512]
  const size_t WL = 14155776;            // per-layer transposed weights (bytes)
  bool up = (ws_size >= o + 12 * WL);
  size_t nsl = up ? 12 : 1;
  u16* qkvt = (u16*)(ws + o);
  u16* wot  = qkvt + nsl * 2304 * 768;
  u16* fct  = wot  + nsl * 768 * 768;
  u16* prt  = fct  + nsl * 3072 * 768;

  auto trans = [&](const float* src, u16* dst, int K, int N, int Kp, long sIn, long sOut, int nz){
    transw_k<<<dim3(N / 32, Kp / 32, nz), dim3(256), 0, stream>>>(src, dst, K, N, Kp, sIn, sOut);
  };

  if (up) {
    for (int s = 0; s < 2; ++s) {
      for (int p = 0; p < 3; ++p)
        trans(F(8 + 16*s + 2 + 2*p), qkvt + (size_t)s*6*2304*768 + (size_t)p*768*768,
              768, 768, 768, 768L*768, 2304L*768, 6);
      trans(F(8 + 16*s + 8),  wot + (size_t)s*6*768*768,  768, 768, 768, 768L*768, 768L*768, 6);
      trans(F(8 + 16*s + 12), fct + (size_t)s*6*3072*768, 768, 3072, 768, 768L*3072, 3072L*768, 6);
      trans(F(8 + 16*s + 14), prt + (size_t)s*6*768*3072, 3072, 768, 3072, 3072L*768, 768L*3072, 6);
    }
  }
  trans(F(42), hut, 768, 512, 768, 0, 0, 1);
  trans(F(43), hdt, 768, 512, 768, 0, 0, 1);
  trans(cw,    cwt, 438, 768, 448, 0, 0, 1);
  biascat_k<<<dim3(108), dim3(256), 0, stream>>>(F(11), F(13), F(15), F(27), F(29), F(31), qkvb);
  condcvt_k<<<dim3(896), dim3(256), 0, stream>>>(cond, cbf);
  embed_k<<<dim3(768), dim3(256), 0, stream>>>(idx_up, idx_dn, teu, ted, pe, x);
  // cond @ cond_w + cond_b + pos_emb -> x rows b*768 + (0..255)
  gemm_k<64, 64, 32, 32, EPI_PE, true><<<dim3(8, 12, 1), dim3(256), 0, stream>>>(cbf, cwt, cb,
      x, nullptr, nullptr, nullptr, nullptr, pe,
      512, 768, 448, 448, 448, 768, 256, 0, 768, 0, 0);

  for (int l = 0; l < 12; ++l) {
    int s = l / 6, li = l % 6;
    u16* qkvt_l = qkvt + (up ? (size_t)l : 0) * 2304 * 768;
    u16* wot_l  = wot  + (up ? (size_t)l : 0) * 768 * 768;
    u16* fct_l  = fct  + (up ? (size_t)l : 0) * 3072 * 768;
    u16* prt_l  = prt  + (up ? (size_t)l : 0) * 768 * 3072;
    if (!up) {
      for (int p = 0; p < 3; ++p)
        trans(F(8 + 16*s + 2 + 2*p) + (size_t)li*768*768, qkvt_l + (size_t)p*768*768, 768, 768, 768, 0, 0, 1);
      trans(F(8 + 16*s + 8)  + (size_t)li*768*768,  wot_l, 768, 768, 768, 0, 0, 1);
      trans(F(8 + 16*s + 12) + (size_t)li*768*3072, fct_l, 768, 3072, 768, 0, 0, 1);
      trans(F(8 + 16*s + 14) + (size_t)li*3072*768, prt_l, 3072, 768, 3072, 0, 0, 1);
    }
    // LN1 (fused with previous layer's proj2 split-K reduce + residual)
    if (l == 0) {
      lnred_k<0, false><<<dim3(384), dim3(256), 0, stream>>>(x, nullptr, nullptr,
          F(8+16*s+0) + (size_t)li*768, F(8+16*s+1) + (size_t)li*768, nullptr, h);
    } else {
      int ps = (l - 1) / 6, pli = (l - 1) % 6;
      lnred_k<4, true><<<dim3(384), dim3(256), 0, stream>>>(x, P2,
          F(8+16*ps+15) + (size_t)pli*768,
          F(8+16*s+0) + (size_t)li*768, F(8+16*s+1) + (size_t)li*768, x, h);
    }
    gemm_k<128, 128, 64, 64, EPI_QKV, true><<<dim3(12, 18, 1), dim3(256), 0, stream>>>(h, qkvt_l, qkvb + (size_t)l*2304,
        nullptr, nullptr, qbuf, kbuf, vT, nullptr,
        1536, 2304, 768, 768, 768, 768, 256, 0, 256, 0, 0);
    attn_k<<<dim3(24, 24), dim3(128), 0, stream>>>(qbuf, kbuf, vT, y);
    // attn out proj: split-K x2 -> P1
    gemm_k<128, 128, 64, 64, EPI_PART, false><<<dim3(12, 6, 2), dim3(256), 0, stream>>>(y, wot_l, nullptr,
        P1, nullptr, nullptr, nullptr, nullptr, nullptr,
        1536, 768, 384, 768, 768, 768, 256, 0, 256, 0, 1179648);
    // LN2 fused with proj reduce + residual + bo
    lnred_k<2, true><<<dim3(384), dim3(256), 0, stream>>>(x, P1,
        F(8+16*s+9) + (size_t)li*768,
        F(8+16*s+10) + (size_t)li*768, F(8+16*s+11) + (size_t)li*768, x, h);
    gemm_k<128, 128, 64, 64, EPI_GELU, true><<<dim3(12, 24, 1), dim3(256), 0, stream>>>(h, fct_l, F(8+16*s+13) + (size_t)li*3072,
        nullptr, fca, nullptr, nullptr, nullptr, nullptr,
        1536, 3072, 768, 768, 768, 3072, 256, 0, 256, 0, 0);
    // MLP out proj: split-K x4 -> P2 (reduced by next lnred / ln_f)
    gemm_k<128, 128, 64, 64, EPI_PART, false><<<dim3(12, 6, 4), dim3(256), 0, stream>>>(fca, prt_l, nullptr,
        P2, nullptr, nullptr, nullptr, nullptr, nullptr,
        1536, 768, 768, 3072, 3072, 768, 256, 0, 256, 0, 1179648);
  }
  // ln_f fused with last proj2 reduce (x not needed afterwards)
  lnred_k<4, false><<<dim3(384), dim3(256), 0, stream>>>(x, P2,
      F(8+16*1+15) + (size_t)5*768, F(40), F(41), nullptr, xf);
  // heads: split-K x4 each, then fused reduce
  gemm_k<64, 64, 32, 32, EPI_PART, false><<<dim3(8, 8, 4), dim3(256), 0, stream>>>(xf, hut, nullptr,
      HP, nullptr, nullptr, nullptr, nullptr, nullptr,
      512, 512, 192, 768, 768, 512, 768, 256, 256, 0, 262144);
  gemm_k<64, 64, 32, 32, EPI_PART, false><<<dim3(8, 8, 4), dim3(256), 0, stream>>>(xf, hdt, nullptr,
      HP + 1048576, nullptr, nullptr, nullptr, nullptr, nullptr,
      512, 512, 192, 768, 768, 512, 768, 512, 256, 0, 262144);
  headred_k<<<dim3(512), dim3(256), 0, stream>>>(HP, outp);
}

// Round 5
// 1353.981 us; speedup vs baseline: 1.3484x; 1.0481x over previous
//
#include <hip/hip_runtime.h>
#include <cmath>

typedef unsigned short u16;
typedef __bf16 bf16x8 __attribute__((ext_vector_type(8)));
typedef float f32x4 __attribute__((ext_vector_type(4)));
typedef u16 u16x4 __attribute__((ext_vector_type(4)));
typedef u16 u16x2 __attribute__((ext_vector_type(2)));

#define GLOAD16(g, l) __builtin_amdgcn_global_load_lds( \
    (const __attribute__((address_space(1))) unsigned int*)(g), \
    (__attribute__((address_space(3))) unsigned int*)(l), 16, 0, 0)

__device__ __forceinline__ u16 f2b(float f) {
  unsigned u = __builtin_bit_cast(unsigned, f);
  unsigned r = (u + 0x7fffu + ((u >> 16) & 1u)) >> 16;
  return (u16)r;
}

// XCD-aware bijective swizzle (m204): consecutive remapped ids land on one XCD
__device__ __forceinline__ int xcd_swz(int lin, int nwg) {
  int q = nwg >> 3, r = nwg & 7;
  int xcd = lin & 7, idx = lin >> 3;
  return xcd * q + (xcd < r ? xcd : r) + idx;
}

// ---------------- transpose + f32->bf16 convert:  W[K][N] f32 -> Wt[N][Kp] bf16 (zero-pad K..Kp)
__global__ __launch_bounds__(256)
void transw_k(const float* __restrict__ W, u16* __restrict__ Wt,
              int K, int N, int Kp, long sIn, long sOut)
{
  __shared__ float t[32][33];
  int n0 = blockIdx.x * 32, k0 = blockIdx.y * 32, l = blockIdx.z;
  const float* Wl = W + (long)l * sIn;
  u16* Wo = Wt + (long)l * sOut;
  int tx = threadIdx.x & 31, ty = threadIdx.x >> 5;
  #pragma unroll
  for (int i = 0; i < 4; ++i) {
    int k = k0 + ty + i * 8;
    t[ty + i * 8][tx] = (k < K) ? Wl[(long)k * N + n0 + tx] : 0.0f;
  }
  __syncthreads();
  #pragma unroll
  for (int i = 0; i < 2; ++i) {
    int p = threadIdx.x + 256 * i;     // 0..511
    int nl = p >> 4, kk = (p & 15) * 2;
    u16x2 o2; o2[0] = f2b(t[kk][nl]); o2[1] = f2b(t[kk + 1][nl]);
    *(u16x2*)(Wo + (long)(n0 + nl) * Kp + k0 + kk) = o2;
  }
}

// ---------------- concat qkv biases: out[12][2304]
__global__ void biascat_k(const float* bq0, const float* bk0, const float* bv0,
                          const float* bq1, const float* bk1, const float* bv1, float* o)
{
  int idx = blockIdx.x * 256 + threadIdx.x;            // 12*2304
  int c = idx % 2304, l = idx / 2304;
  int st = l / 6, li = l % 6;
  const float* src = (c < 768) ? (st ? bq1 : bq0) : (c < 1536) ? (st ? bk1 : bk0) : (st ? bv1 : bv0);
  o[idx] = src[li * 768 + (c % 768)];
}

// ---------------- cond f32 [512][438] -> bf16 [512][448] zero-padded
__global__ void condcvt_k(const float* __restrict__ c, u16* __restrict__ o)
{
  int idx = blockIdx.x * 256 + threadIdx.x;            // 512*448
  int k = idx % 448, r = idx / 448;
  o[idx] = f2b(k < 438 ? c[r * 438 + k] : 0.0f);
}

// ---------------- token embeddings + pos_emb for streams 1,2 -> x f32
__global__ void embed_k(const int* __restrict__ iu, const int* __restrict__ idn,
                        const float* __restrict__ teu, const float* __restrict__ ted,
                        const float* __restrict__ pe, float* __restrict__ x)
{
  int idx = blockIdx.x * 256 + threadIdx.x;            // 2*512*192
  int c4 = idx % 192; int rest = idx / 192;
  int tt = rest % 512; int b = rest / 512;
  int i = tt & 255; int s = tt >> 8;
  int tok = s ? idn[b * 256 + i] : iu[b * 256 + i];
  const float4* src = (const float4*)(s ? (ted + (long)tok * 768) : (teu + (long)tok * 768));
  int prow = 256 + s * 256 + i;
  float4 pv = ((const float4*)(pe + (long)prow * 768))[c4];
  float4 sv = src[c4];
  float4 ov; ov.x = sv.x + pv.x; ov.y = sv.y + pv.y; ov.z = sv.z + pv.z; ov.w = sv.w + pv.w;
  ((float4*)(x + ((long)b * 768 + prow) * 768))[c4] = ov;
}

// ---------------- fused split-K reduce + residual + bias + LayerNorm (float4-vectorized)
template<int S, bool WX>
__global__ __launch_bounds__(256)
void lnred_k(const float* __restrict__ xin, const float* __restrict__ P,
             const float* __restrict__ bias, const float* __restrict__ gg,
             const float* __restrict__ bb, float* __restrict__ xout,
             u16* __restrict__ h)
{
  int row = blockIdx.x * 4 + (threadIdx.x >> 6);
  int lane = threadIdx.x & 63;
  long base = (long)row * 768;
  const float4* xr4 = (const float4*)(xin + base);
  float4 v[3]; float s = 0.0f;
  #pragma unroll
  for (int j = 0; j < 3; ++j) {
    int f = lane + 64 * j;
    float4 val = xr4[f];
    if (S > 0) {
      float4 bv = ((const float4*)bias)[f];
      val.x += bv.x; val.y += bv.y; val.z += bv.z; val.w += bv.w;
      #pragma unroll
      for (int si = 0; si < S; ++si) {
        float4 pv = ((const float4*)(P + (long)si * 1179648 + base))[f];
        val.x += pv.x; val.y += pv.y; val.z += pv.z; val.w += pv.w;
      }
    }
    if (WX) ((float4*)(xout + base))[f] = val;
    v[j] = val; s += val.x + val.y + val.z + val.w;
  }
  #pragma unroll
  for (int d = 1; d < 64; d <<= 1) s += __shfl_xor(s, d);
  float mean = s * (1.0f / 768.0f);
  float s2 = 0.0f;
  #pragma unroll
  for (int j = 0; j < 3; ++j) {
    float dx = v[j].x - mean, dy = v[j].y - mean, dz = v[j].z - mean, dw = v[j].w - mean;
    s2 += dx * dx + dy * dy + dz * dz + dw * dw;
  }
  #pragma unroll
  for (int d = 1; d < 64; d <<= 1) s2 += __shfl_xor(s2, d);
  float rstd = rsqrtf(s2 * (1.0f / 768.0f) + 1e-5f);
  u16* orow = h + base;
  #pragma unroll
  for (int j = 0; j < 3; ++j) {
    int f = lane + 64 * j;
    float4 gv = ((const float4*)gg)[f];
    float4 bv2 = ((const float4*)bb)[f];
    u16x4 pk;
    pk[0] = f2b((v[j].x - mean) * rstd * gv.x + bv2.x);
    pk[1] = f2b((v[j].y - mean) * rstd * gv.y + bv2.y);
    pk[2] = f2b((v[j].z - mean) * rstd * gv.z + bv2.z);
    pk[3] = f2b((v[j].w - mean) * rstd * gv.w + bv2.w);
    *(u16x4*)(orow + 4 * f) = pk;
  }
}

// ---------------- heads reduce: out[2][512][512] = sum of 4 partial slabs each
__global__ __launch_bounds__(256)
void headred_k(const float* __restrict__ HP, float* __restrict__ out)
{
  int i4 = blockIdx.x * 256 + threadIdx.x;   // 131072 float4 groups
  int st = i4 >> 16, loc = i4 & 65535;
  const float4* basep = (const float4*)HP + (long)st * 4 * 65536 + loc;
  float4 a = basep[0], b = basep[65536], c = basep[2 * 65536], d = basep[3 * 65536];
  float4 r; r.x = a.x + b.x + c.x + d.x; r.y = a.y + b.y + c.y + d.y;
  r.z = a.z + b.z + c.z + d.z; r.w = a.w + b.w + c.w + d.w;
  ((float4*)out)[i4] = r;
}

// ---------------- GEMM: C[M,N] = A[M,K](bf16) @ Bt[N,K](bf16)^T
// templated tile: BM x BN block, WM x WN per wave, BK=64, ring-2 LDS, XCD swizzle
#define EPI_PLAIN 0
#define EPI_PE    1
#define EPI_QKV   2
#define EPI_GELU  4
#define EPI_PART  5

template<int BM, int BN, int WM, int WN, int EPI, bool BIAS>
__global__ __launch_bounds__(256)
void gemm_k(const u16* __restrict__ A, const u16* __restrict__ Bt, const float* __restrict__ bias,
            float* outf, u16* outb, u16* qb, u16* kb, u16* vT, const float* aux,
            int M, int N, int Ks, int lda, int ldb, int ldc,
            int astr, int aoff, int cstr, int coff, int pstr)
{
  constexpr int NWC = BN / WN;               // waves along N
  constexpr int NT  = (BM / WM) * NWC * 64;  // threads (=256 for all configs used)
  constexpr int LCH = (BM + BN) * 8;         // 16B chunks per buffer
  constexpr int LPT = LCH / NT;              // global_load_lds per thread per stage
  constexpr int MR = WM / 16, NR = WN / 16;
  __shared__ alignas(16) u16 Sl[2][(BM + BN) * 64];

  const int tid = threadIdx.x;
  // XCD swizzle: y-panel-major linearization, contiguous chunk per XCD
  const int gx = gridDim.x, gy = gridDim.y;
  const int nwg = gx * gy * gridDim.z;
  const int lin = (blockIdx.z * gy + blockIdx.y) * gx + blockIdx.x;
  const int wg = xcd_swz(lin, nwg);
  const int bx = wg % gx, t1g = wg / gx;
  const int by = t1g % gy, bz = t1g / gy;
  const int m0 = bx * BM, n0 = by * BN;
  const int koff = bz * Ks;
  const int lane = tid & 63, w = tid >> 6, l15 = lane & 15, g = lane >> 4;
  const int wr = w / NWC, wc = w % NWC;

  // staging chunk c = tid + NT*j; chunk -> (region,row,slot); swizzled SOURCE, linear DEST
  const u16* gp[LPT]; int lbase[LPT];
  #pragma unroll
  for (int j = 0; j < LPT; ++j) {
    int c = tid + NT * j;
    int slot = c & 7;
    if (c < BM * 8) {
      int row = c >> 3;
      int se = (slot ^ (row & 7)) * 8;
      int am = m0 + row;
      gp[j] = A + (long)((am >> 8) * astr + aoff + (am & 255)) * lda + koff + se;
    } else {
      int rb = c - BM * 8;
      int row = rb >> 3;
      int se = (slot ^ (row & 7)) * 8;
      gp[j] = Bt + (long)(n0 + row) * ldb + koff + se;
    }
    lbase[j] = w * 512 + NT * 8 * j;         // wave-uniform LDS base (u16 elems)
  }

  // ds_read byte offsets: [ks][frag]
  int offA[2][MR], offB[2][NR];
  #pragma unroll
  for (int ks = 0; ks < 2; ++ks) {
    int s = 4 * ks + g;
    #pragma unroll
    for (int mi = 0; mi < MR; ++mi) {
      int r = wr * WM + mi * 16 + l15;
      offA[ks][mi] = r * 128 + ((s ^ (r & 7)) << 4);
    }
    #pragma unroll
    for (int ni = 0; ni < NR; ++ni) {
      int r = wc * WN + ni * 16 + l15;
      offB[ks][ni] = BM * 128 + r * 128 + ((s ^ (r & 7)) << 4);
    }
  }

  f32x4 acc[MR][NR];
  #pragma unroll
  for (int mi = 0; mi < MR; ++mi)
  #pragma unroll
  for (int ni = 0; ni < NR; ++ni) acc[mi][ni] = f32x4{};

  auto STAGE = [&](int kt, int buf) {
    #pragma unroll
    for (int j = 0; j < LPT; ++j) GLOAD16(gp[j] + kt, &Sl[buf][lbase[j]]);
  };
  auto COMPUTE = [&](int buf) {
    const char* Sb = (const char*)&Sl[buf][0];
    #pragma unroll
    for (int ks = 0; ks < 2; ++ks) {
      bf16x8 a[MR], b[NR];
      #pragma unroll
      for (int mi = 0; mi < MR; ++mi) a[mi] = *(const bf16x8*)(Sb + offA[ks][mi]);
      #pragma unroll
      for (int ni = 0; ni < NR; ++ni) b[ni] = *(const bf16x8*)(Sb + offB[ks][ni]);
      #pragma unroll
      for (int mi = 0; mi < MR; ++mi)
      #pragma unroll
      for (int ni = 0; ni < NR; ++ni)
        acc[mi][ni] = __builtin_amdgcn_mfma_f32_16x16x32_bf16(a[mi], b[ni], acc[mi][ni], 0, 0, 0);
    }
  };

  const int nIter = Ks >> 6;
  STAGE(0, 0);
  if (nIter > 1) STAGE(64, 1);
  for (int t = 0; t < nIter; ++t) {
    if (t + 1 < nIter) {
      if constexpr (LPT == 8) asm volatile("s_waitcnt vmcnt(8)" ::: "memory");
      else                    asm volatile("s_waitcnt vmcnt(4)" ::: "memory");
    } else {
      asm volatile("s_waitcnt vmcnt(0)" ::: "memory");
    }
    __builtin_amdgcn_s_barrier();            // all waves' stage-t landed
    COMPUTE(t & 1);
    if (t + 2 < nIter) {
      __builtin_amdgcn_s_barrier();          // all waves done reading buf[t&1]
      STAGE((t + 2) << 6, t & 1);
    }
  }

  #pragma unroll
  for (int mi = 0; mi < MR; ++mi)
  #pragma unroll
  for (int ni = 0; ni < NR; ++ni) {
    f32x4 a = acc[mi][ni];
    int col = n0 + wc * WN + ni * 16 + l15;
    float bv = BIAS ? bias[col] : 0.0f;
    int mlb = m0 + wr * WM + mi * 16 + 4 * g;
    if (EPI == EPI_QKV) {
      if (col >= 1536) {
        int c2 = col - 1536, hh = c2 >> 6, dd = c2 & 63;
        int bb2 = mlb >= 768 ? 1 : 0;
        int t0 = mlb - bb2 * 768;
        u16x4 pk;
        #pragma unroll
        for (int r = 0; r < 4; ++r) pk[r] = f2b(a[r] + bv);
        *(u16x4*)(vT + (long)((bb2 * 12 + hh) * 64 + dd) * 768 + t0) = pk;
      } else {
        u16* dst = (col < 768) ? (qb + (long)mlb * 768 + col) : (kb + (long)mlb * 768 + (col - 768));
        #pragma unroll
        for (int r = 0; r < 4; ++r) dst[(long)r * 768] = f2b(a[r] + bv);
      }
    } else {
      #pragma unroll
      for (int r = 0; r < 4; ++r) {
        int rg = mlb + r;
        long crow = (long)(rg >> 8) * cstr + coff + (rg & 255);
        float v = a[r] + bv;
        if (EPI == EPI_PLAIN)      outf[crow * ldc + col] = v;
        else if (EPI == EPI_PE)    outf[crow * ldc + col] = v + aux[(long)(rg & 255) * 768 + col];
        else if (EPI == EPI_PART)  outf[(long)bz * pstr + (long)rg * ldc + col] = v;
        else if (EPI == EPI_GELU)  outb[crow * ldc + col] = f2b(0.5f * v * (1.0f + erff(v * 0.70710678f)));
      }
    }
  }
}

// ---------------- flash attention: 32 q-rows / 2 waves per WG, masked-tile skipping
#define MFMA_BF16 __builtin_amdgcn_mfma_f32_16x16x32_bf16
__global__ __launch_bounds__(128)
void attn_k(const u16* __restrict__ qb, const u16* __restrict__ kb,
            const u16* __restrict__ vT, u16* __restrict__ y)
{
  __shared__ alignas(16) u16 Kl[3 * 4096];
  __shared__ alignas(16) u16 Vl[3 * 4096];
  __shared__ alignas(16) u16 Pl[2][16 * 72];
  // XCD swizzle: bh-major linearization so same-bh blocks share an XCD's L2
  const int gx = gridDim.x, gy = gridDim.y;
  const int nwg = gx * gy;
  const int lin = blockIdx.y * gx + blockIdx.x;
  const int wg = xcd_swz(lin, nwg);
  const int qt = wg % gx, bh = wg / gx;
  const int b = bh / 12, h = bh - b * 12;
  const int tid = threadIdx.x, w = tid >> 6, lane = tid & 63, l15 = lane & 15, g = lane >> 4;
  const int qrow = qt * 32 + w * 16 + l15;
  const int qm = qrow & 255;
  const int q0 = (qt * 32) & 255;
  const unsigned nw4 = (q0 >> 6) + 1;
  const int niter = 3 * nw4;
  const u16* qp = qb + (long)(b * 768 + qrow) * 768 + h * 64;
  bf16x8 qf0 = *(const bf16x8*)(qp + 8 * g);
  bf16x8 qf1 = *(const bf16x8*)(qp + 32 + 8 * g);
  f32x4 O0{}, O1{}, O2{}, O3{};
  float m_run = -1e30f, l_run = 0.0f;

  const u16* kp[4]; const u16* vp[4]; int ldsb[4];
  #pragma unroll
  for (int j = 0; j < 4; ++j) {
    int i = tid + 128 * j;
    int r = i >> 3, sl = ((i & 7) ^ (r & 7)) * 8;
    kp[j] = kb + (long)(b * 768 + r) * 768 + h * 64 + sl;
    vp[j] = vT + (long)(bh * 64 + r) * 768 + sl;
    ldsb[j] = (w + 2 * j) * 512;
  }

  auto STAGE = [&](int kt, int q) {
    u16* kd = Kl + q * 4096; u16* vd = Vl + q * 4096;
    #pragma unroll
    for (int j = 0; j < 4; ++j) GLOAD16(kp[j] + (long)kt * 64 * 768, kd + ldsb[j]);
    #pragma unroll
    for (int j = 0; j < 4; ++j) GLOAD16(vp[j] + kt * 64, vd + ldsb[j]);
  };
  auto MAP = [&](int it) {
    unsigned sb = (unsigned)it / nw4;
    return (int)(sb * 4 + ((unsigned)it - sb * nw4));
  };

  STAGE(MAP(0), 0);
  STAGE(MAP(1), 1);
  int cur = 0;
  for (int it = 0; it < niter; ++it) {
    if (it < niter - 1) asm volatile("s_waitcnt vmcnt(8)" ::: "memory");
    else                asm volatile("s_waitcnt vmcnt(0)" ::: "memory");
    __builtin_amdgcn_s_barrier();
    if (it + 2 < niter) STAGE(MAP(it + 2), cur == 0 ? 2 : cur - 1);
    const int kt = MAP(it);
    const char* Kb = (const char*)Kl + cur * 8192;
    const char* Vb = (const char*)Vl + cur * 8192;

    f32x4 s0{}, s1{}, s2{}, s3{};
    #pragma unroll
    for (int ks = 0; ks < 2; ++ks) {
      bf16x8 qf = ks ? qf1 : qf0;
      int sb = ((4 * ks + g) ^ (l15 & 7)) << 4;
      bf16x8 k0 = *(const bf16x8*)(Kb + (0  + l15) * 128 + sb);
      bf16x8 k1 = *(const bf16x8*)(Kb + (16 + l15) * 128 + sb);
      bf16x8 k2 = *(const bf16x8*)(Kb + (32 + l15) * 128 + sb);
      bf16x8 k3 = *(const bf16x8*)(Kb + (48 + l15) * 128 + sb);
      s0 = MFMA_BF16(k0, qf, s0, 0, 0, 0);
      s1 = MFMA_BF16(k1, qf, s1, 0, 0, 0);
      s2 = MFMA_BF16(k2, qf, s2, 0, 0, 0);
      s3 = MFMA_BF16(k3, qf, s3, 0, 0, 0);
    }
    float sv[16]; float tm = -1e30f;
    #pragma unroll
    for (int mt = 0; mt < 4; ++mt) {
      f32x4 sm4 = (mt == 0) ? s0 : (mt == 1) ? s1 : (mt == 2) ? s2 : s3;
      #pragma unroll
      for (int r = 0; r < 4; ++r) {
        int kg = kt * 64 + mt * 16 + 4 * g + r;
        float val = ((kg & 255) <= qm) ? sm4[r] * 0.125f : -1e30f;
        sv[mt * 4 + r] = val; tm = fmaxf(tm, val);
      }
    }
    tm = fmaxf(tm, __shfl_xor(tm, 16));
    tm = fmaxf(tm, __shfl_xor(tm, 32));
    float mn = fmaxf(m_run, tm);
    float alpha = __expf(m_run - mn);
    float ps = 0.0f; u16 pb16[16];
    #pragma unroll
    for (int j = 0; j < 16; ++j) {
      float p = (sv[j] <= -1e29f) ? 0.0f : __expf(sv[j] - mn);
      ps += p; pb16[j] = f2b(p);
    }
    ps += __shfl_xor(ps, 16); ps += __shfl_xor(ps, 32);
    l_run = l_run * alpha + ps; m_run = mn;
    float a0 = __shfl(alpha, 4 * g + 0);
    float a1 = __shfl(alpha, 4 * g + 1);
    float a2 = __shfl(alpha, 4 * g + 2);
    float a3 = __shfl(alpha, 4 * g + 3);
    #pragma unroll
    for (int mt = 0; mt < 4; ++mt) {
      u16x4 pk; pk[0] = pb16[4*mt]; pk[1] = pb16[4*mt+1]; pk[2] = pb16[4*mt+2]; pk[3] = pb16[4*mt+3];
      *(u16x4*)((char*)&Pl[w][0] + l15 * 144 + mt * 32 + 8 * g) = pk;
    }
    O0[0] *= a0; O0[1] *= a1; O0[2] *= a2; O0[3] *= a3;
    O1[0] *= a0; O1[1] *= a1; O1[2] *= a2; O1[3] *= a3;
    O2[0] *= a0; O2[1] *= a1; O2[2] *= a2; O2[3] *= a3;
    O3[0] *= a0; O3[1] *= a1; O3[2] *= a2; O3[3] *= a3;
    asm volatile("s_waitcnt lgkmcnt(0)" ::: "memory");
    __builtin_amdgcn_sched_barrier(0);
    #pragma unroll
    for (int ks = 0; ks < 2; ++ks) {
      bf16x8 pf = *(const bf16x8*)((const char*)&Pl[w][0] + l15 * 144 + 64 * ks + 16 * g);
      int sb = ((4 * ks + g) ^ (l15 & 7)) << 4;
      bf16x8 v0 = *(const bf16x8*)(Vb + (0  + l15) * 128 + sb);
      bf16x8 v1 = *(const bf16x8*)(Vb + (16 + l15) * 128 + sb);
      bf16x8 v2 = *(const bf16x8*)(Vb + (32 + l15) * 128 + sb);
      bf16x8 v3 = *(const bf16x8*)(Vb + (48 + l15) * 128 + sb);
      O0 = MFMA_BF16(pf, v0, O0, 0, 0, 0);
      O1 = MFMA_BF16(pf, v1, O1, 0, 0, 0);
      O2 = MFMA_BF16(pf, v2, O2, 0, 0, 0);
      O3 = MFMA_BF16(pf, v3, O3, 0, 0, 0);
    }
    cur = (cur == 2) ? 0 : cur + 1;
  }
  float n0i = 1.0f / __shfl(l_run, 4 * g + 0);
  float n1i = 1.0f / __shfl(l_run, 4 * g + 1);
  float n2i = 1.0f / __shfl(l_run, 4 * g + 2);
  float n3i = 1.0f / __shfl(l_run, 4 * g + 3);
  long yr = (long)(b * 768 + qt * 32 + w * 16 + 4 * g);
  #pragma unroll
  for (int ni = 0; ni < 4; ++ni) {
    f32x4 Ov = (ni == 0) ? O0 : (ni == 1) ? O1 : (ni == 2) ? O2 : O3;
    int c = h * 64 + ni * 16 + l15;
    y[(yr + 0) * 768 + c] = f2b(Ov[0] * n0i);
    y[(yr + 1) * 768 + c] = f2b(Ov[1] * n1i);
    y[(yr + 2) * 768 + c] = f2b(Ov[2] * n2i);
    y[(yr + 3) * 768 + c] = f2b(Ov[3] * n3i);
  }
}

// ================= host =================
extern "C" void kernel_launch(void* const* d_in, const int* in_sizes, int n_in,
                              void* d_out, int out_size, void* d_ws, size_t ws_size,
                              hipStream_t stream)
{
  (void)in_sizes; (void)n_in; (void)out_size;
  auto F = [&](int i){ return (const float*)d_in[i]; };
  const int* idx_up = (const int*)d_in[0];
  const int* idx_dn = (const int*)d_in[1];
  const float* cond = F(2);
  const float* teu = F(3);
  const float* ted = F(4);
  const float* pe  = F(5);
  const float* cw  = F(6);
  const float* cb  = F(7);
  float* outp = (float*)d_out;
  char* ws = (char*)d_ws;

  size_t o = 0;
  auto take = [&](size_t bytes){ void* p = ws + o; o += bytes; return p; };
  float* x    = (float*)take(4718592);   // [1536][768] f32 residual stream
  u16*   h    = (u16*)take(2359296);     // LN out bf16
  u16*   qbuf = (u16*)take(2359296);
  u16*   kbuf = (u16*)take(2359296);
  u16*   vT   = (u16*)take(2359296);     // [24][64][768]
  u16*   y    = (u16*)take(2359296);
  u16*   fca  = (u16*)take(9437184);     // [1536][3072]
  u16*   xf   = (u16*)take(2359296);
  u16*   cbf  = (u16*)take(458752);      // cond bf16 [512][448]
  float* qkvb = (float*)take(110592);    // [12][2304]
  u16*   hut  = (u16*)take(786432);
  u16*   hdt  = (u16*)take(786432);
  u16*   cwt  = (u16*)take(688128);      // [768][448]
  float* P1   = (float*)take(9437184);   // proj partials  [2][1536][768]
  float* P2   = (float*)take(18874368);  // proj2 partials [4][1536][768]
  float* HP   = (float*)take(8388608);   // head partials  [2][4][512][512]
  const size_t WL = 14155776;            // per-layer transposed weights (bytes)
  bool up = (ws_size >= o + 12 * WL);
  size_t nsl = up ? 12 : 1;
  u16* qkvt = (u16*)(ws + o);
  u16* wot  = qkvt + nsl * 2304 * 768;
  u16* fct  = wot  + nsl * 768 * 768;
  u16* prt  = fct  + nsl * 3072 * 768;

  auto trans = [&](const float* src, u16* dst, int K, int N, int Kp, long sIn, long sOut, int nz){
    transw_k<<<dim3(N / 32, Kp / 32, nz), dim3(256), 0, stream>>>(src, dst, K, N, Kp, sIn, sOut);
  };

  if (up) {
    for (int s = 0; s < 2; ++s) {
      for (int p = 0; p < 3; ++p)
        trans(F(8 + 16*s + 2 + 2*p), qkvt + (size_t)s*6*2304*768 + (size_t)p*768*768,
              768, 768, 768, 768L*768, 2304L*768, 6);
      trans(F(8 + 16*s + 8),  wot + (size_t)s*6*768*768,  768, 768, 768, 768L*768, 768L*768, 6);
      trans(F(8 + 16*s + 12), fct + (size_t)s*6*3072*768, 768, 3072, 768, 768L*3072, 3072L*768, 6);
      trans(F(8 + 16*s + 14), prt + (size_t)s*6*768*3072, 3072, 768, 3072, 3072L*768, 768L*3072, 6);
    }
  }
  trans(F(42), hut, 768, 512, 768, 0, 0, 1);
  trans(F(43), hdt, 768, 512, 768, 0, 0, 1);
  trans(cw,    cwt, 438, 768, 448, 0, 0, 1);
  biascat_k<<<dim3(108), dim3(256), 0, stream>>>(F(11), F(13), F(15), F(27), F(29), F(31), qkvb);
  condcvt_k<<<dim3(896), dim3(256), 0, stream>>>(cond, cbf);
  embed_k<<<dim3(768), dim3(256), 0, stream>>>(idx_up, idx_dn, teu, ted, pe, x);
  // cond @ cond_w + cond_b + pos_emb -> x rows b*768 + (0..255)
  gemm_k<64, 64, 32, 32, EPI_PE, true><<<dim3(8, 12, 1), dim3(256), 0, stream>>>(cbf, cwt, cb,
      x, nullptr, nullptr, nullptr, nullptr, pe,
      512, 768, 448, 448, 448, 768, 256, 0, 768, 0, 0);

  for (int l = 0; l < 12; ++l) {
    int s = l / 6, li = l % 6;
    u16* qkvt_l = qkvt + (up ? (size_t)l : 0) * 2304 * 768;
    u16* wot_l  = wot  + (up ? (size_t)l : 0) * 768 * 768;
    u16* fct_l  = fct  + (up ? (size_t)l : 0) * 3072 * 768;
    u16* prt_l  = prt  + (up ? (size_t)l : 0) * 768 * 3072;
    if (!up) {
      for (int p = 0; p < 3; ++p)
        trans(F(8 + 16*s + 2 + 2*p) + (size_t)li*768*768, qkvt_l + (size_t)p*768*768, 768, 768, 768, 0, 0, 1);
      trans(F(8 + 16*s + 8)  + (size_t)li*768*768,  wot_l, 768, 768, 768, 0, 0, 1);
      trans(F(8 + 16*s + 12) + (size_t)li*768*3072, fct_l, 768, 3072, 768, 0, 0, 1);
      trans(F(8 + 16*s + 14) + (size_t)li*3072*768, prt_l, 3072, 768, 3072, 0, 0, 1);
    }
    // LN1 (fused with previous layer's proj2 split-K reduce + residual)
    if (l == 0) {
      lnred_k<0, false><<<dim3(384), dim3(256), 0, stream>>>(x, nullptr, nullptr,
          F(8+16*s+0) + (size_t)li*768, F(8+16*s+1) + (size_t)li*768, nullptr, h);
    } else {
      int ps = (l - 1) / 6, pli = (l - 1) % 6;
      lnred_k<4, true><<<dim3(384), dim3(256), 0, stream>>>(x, P2,
          F(8+16*ps+15) + (size_t)pli*768,
          F(8+16*s+0) + (size_t)li*768, F(8+16*s+1) + (size_t)li*768, x, h);
    }
    gemm_k<128, 128, 64, 64, EPI_QKV, true><<<dim3(12, 18, 1), dim3(256), 0, stream>>>(h, qkvt_l, qkvb + (size_t)l*2304,
        nullptr, nullptr, qbuf, kbuf, vT, nullptr,
        1536, 2304, 768, 768, 768, 768, 256, 0, 256, 0, 0);
    attn_k<<<dim3(24, 24), dim3(128), 0, stream>>>(qbuf, kbuf, vT, y);
    // attn out proj: split-K x2 -> P1
    gemm_k<128, 128, 64, 64, EPI_PART, false><<<dim3(12, 6, 2), dim3(256), 0, stream>>>(y, wot_l, nullptr,
        P1, nullptr, nullptr, nullptr, nullptr, nullptr,
        1536, 768, 384, 768, 768, 768, 256, 0, 256, 0, 1179648);
    // LN2 fused with proj reduce + residual + bo
    lnred_k<2, true><<<dim3(384), dim3(256), 0, stream>>>(x, P1,
        F(8+16*s+9) + (size_t)li*768,
        F(8+16*s+10) + (size_t)li*768, F(8+16*s+11) + (size_t)li*768, x, h);
    gemm_k<128, 128, 64, 64, EPI_GELU, true><<<dim3(12, 24, 1), dim3(256), 0, stream>>>(h, fct_l, F(8+16*s+13) + (size_t)li*3072,
        nullptr, fca, nullptr, nullptr, nullptr, nullptr,
        1536, 3072, 768, 768, 768, 3072, 256, 0, 256, 0, 0);
    // MLP out proj: split-K x4 -> P2 (reduced by next lnred / ln_f)
    gemm_k<128, 128, 64, 64, EPI_PART, false><<<dim3(12, 6, 4), dim3(256), 0, stream>>>(fca, prt_l, nullptr,
        P2, nullptr, nullptr, nullptr, nullptr, nullptr,
        1536, 768, 768, 3072, 3072, 768, 256, 0, 256, 0, 1179648);
  }
  // ln_f fused with last proj2 reduce (x not needed afterwards)
  lnred_k<4, false><<<dim3(384), dim3(256), 0, stream>>>(x, P2,
      F(8+16*1+15) + (size_t)5*768, F(40), F(41), nullptr, xf);
  // heads: split-K x4 each, then fused reduce
  gemm_k<64, 64, 32, 32, EPI_PART, false><<<dim3(8, 8, 4), dim3(256), 0, stream>>>(xf, hut, nullptr,
      HP, nullptr, nullptr, nullptr, nullptr, nullptr,
      512, 512, 192, 768, 768, 512, 768, 256, 256, 0, 262144);
  gemm_k<64, 64, 32, 32, EPI_PART, false><<<dim3(8, 8, 4), dim3(256), 0, stream>>>(xf, hdt, nullptr,
      HP + 1048576, nullptr, nullptr, nullptr, nullptr, nullptr,
      512, 512, 192, 768, 768, 512, 768, 512, 256, 0, 262144);
  headred_k<<<dim3(512), dim3(256), 0, stream>>>(HP, outp);
}

// Round 6
// 1290.929 us; speedup vs baseline: 1.4142x; 1.0488x over previous
//
#include <hip/hip_runtime.h>
#include <cmath>

typedef unsigned short u16;
typedef __bf16 bf16x8 __attribute__((ext_vector_type(8)));
typedef float f32x4 __attribute__((ext_vector_type(4)));
typedef u16 u16x4 __attribute__((ext_vector_type(4)));
typedef u16 u16x2 __attribute__((ext_vector_type(2)));

#define GLOAD16(g, l) __builtin_amdgcn_global_load_lds( \
    (const __attribute__((address_space(1))) unsigned int*)(g), \
    (__attribute__((address_space(3))) unsigned int*)(l), 16, 0, 0)

__device__ __forceinline__ u16 f2b(float f) {
  unsigned u = __builtin_bit_cast(unsigned, f);
  unsigned r = (u + 0x7fffu + ((u >> 16) & 1u)) >> 16;
  return (u16)r;
}

// XCD-aware bijective swizzle (m204): consecutive remapped ids land on one XCD
__device__ __forceinline__ int xcd_swz(int lin, int nwg) {
  int q = nwg >> 3, r = nwg & 7;
  int xcd = lin & 7, idx = lin >> 3;
  return xcd * q + (xcd < r ? xcd : r) + idx;
}

// ---------------- transpose + f32->bf16 convert:  W[K][N] f32 -> Wt[N][Kp] bf16 (zero-pad K..Kp)
__global__ __launch_bounds__(256)
void transw_k(const float* __restrict__ W, u16* __restrict__ Wt,
              int K, int N, int Kp, long sIn, long sOut)
{
  __shared__ float t[32][33];
  int n0 = blockIdx.x * 32, k0 = blockIdx.y * 32, l = blockIdx.z;
  const float* Wl = W + (long)l * sIn;
  u16* Wo = Wt + (long)l * sOut;
  int tx = threadIdx.x & 31, ty = threadIdx.x >> 5;
  #pragma unroll
  for (int i = 0; i < 4; ++i) {
    int k = k0 + ty + i * 8;
    t[ty + i * 8][tx] = (k < K) ? Wl[(long)k * N + n0 + tx] : 0.0f;
  }
  __syncthreads();
  #pragma unroll
  for (int i = 0; i < 2; ++i) {
    int p = threadIdx.x + 256 * i;     // 0..511
    int nl = p >> 4, kk = (p & 15) * 2;
    u16x2 o2; o2[0] = f2b(t[kk][nl]); o2[1] = f2b(t[kk + 1][nl]);
    *(u16x2*)(Wo + (long)(n0 + nl) * Kp + k0 + kk) = o2;
  }
}

// ---------------- concat qkv biases: out[12][2304]
__global__ void biascat_k(const float* bq0, const float* bk0, const float* bv0,
                          const float* bq1, const float* bk1, const float* bv1, float* o)
{
  int idx = blockIdx.x * 256 + threadIdx.x;            // 12*2304
  int c = idx % 2304, l = idx / 2304;
  int st = l / 6, li = l % 6;
  const float* src = (c < 768) ? (st ? bq1 : bq0) : (c < 1536) ? (st ? bk1 : bk0) : (st ? bv1 : bv0);
  o[idx] = src[li * 768 + (c % 768)];
}

// ---------------- cond f32 [512][438] -> bf16 [512][448] zero-padded
__global__ void condcvt_k(const float* __restrict__ c, u16* __restrict__ o)
{
  int idx = blockIdx.x * 256 + threadIdx.x;            // 512*448
  int k = idx % 448, r = idx / 448;
  o[idx] = f2b(k < 438 ? c[r * 438 + k] : 0.0f);
}

// ---------------- token embeddings + pos_emb for streams 1,2 -> x f32
__global__ void embed_k(const int* __restrict__ iu, const int* __restrict__ idn,
                        const float* __restrict__ teu, const float* __restrict__ ted,
                        const float* __restrict__ pe, float* __restrict__ x)
{
  int idx = blockIdx.x * 256 + threadIdx.x;            // 2*512*192
  int c4 = idx % 192; int rest = idx / 192;
  int tt = rest % 512; int b = rest / 512;
  int i = tt & 255; int s = tt >> 8;
  int tok = s ? idn[b * 256 + i] : iu[b * 256 + i];
  const float4* src = (const float4*)(s ? (ted + (long)tok * 768) : (teu + (long)tok * 768));
  int prow = 256 + s * 256 + i;
  float4 pv = ((const float4*)(pe + (long)prow * 768))[c4];
  float4 sv = src[c4];
  float4 ov; ov.x = sv.x + pv.x; ov.y = sv.y + pv.y; ov.z = sv.z + pv.z; ov.w = sv.w + pv.w;
  ((float4*)(x + ((long)b * 768 + prow) * 768))[c4] = ov;
}

// ---------------- fused split-K reduce + residual + bias + LayerNorm (float4-vectorized)
template<int S, bool WX>
__global__ __launch_bounds__(256)
void lnred_k(const float* __restrict__ xin, const float* __restrict__ P,
             const float* __restrict__ bias, const float* __restrict__ gg,
             const float* __restrict__ bb, float* __restrict__ xout,
             u16* __restrict__ h)
{
  int row = blockIdx.x * 4 + (threadIdx.x >> 6);
  int lane = threadIdx.x & 63;
  long base = (long)row * 768;
  const float4* xr4 = (const float4*)(xin + base);
  float4 v[3]; float s = 0.0f;
  #pragma unroll
  for (int j = 0; j < 3; ++j) {
    int f = lane + 64 * j;
    float4 val = xr4[f];
    if (S > 0) {
      float4 bv = ((const float4*)bias)[f];
      val.x += bv.x; val.y += bv.y; val.z += bv.z; val.w += bv.w;
      #pragma unroll
      for (int si = 0; si < S; ++si) {
        float4 pv = ((const float4*)(P + (long)si * 1179648 + base))[f];
        val.x += pv.x; val.y += pv.y; val.z += pv.z; val.w += pv.w;
      }
    }
    if (WX) ((float4*)(xout + base))[f] = val;
    v[j] = val; s += val.x + val.y + val.z + val.w;
  }
  #pragma unroll
  for (int d = 1; d < 64; d <<= 1) s += __shfl_xor(s, d);
  float mean = s * (1.0f / 768.0f);
  float s2 = 0.0f;
  #pragma unroll
  for (int j = 0; j < 3; ++j) {
    float dx = v[j].x - mean, dy = v[j].y - mean, dz = v[j].z - mean, dw = v[j].w - mean;
    s2 += dx * dx + dy * dy + dz * dz + dw * dw;
  }
  #pragma unroll
  for (int d = 1; d < 64; d <<= 1) s2 += __shfl_xor(s2, d);
  float rstd = rsqrtf(s2 * (1.0f / 768.0f) + 1e-5f);
  u16* orow = h + base;
  #pragma unroll
  for (int j = 0; j < 3; ++j) {
    int f = lane + 64 * j;
    float4 gv = ((const float4*)gg)[f];
    float4 bv2 = ((const float4*)bb)[f];
    u16x4 pk;
    pk[0] = f2b((v[j].x - mean) * rstd * gv.x + bv2.x);
    pk[1] = f2b((v[j].y - mean) * rstd * gv.y + bv2.y);
    pk[2] = f2b((v[j].z - mean) * rstd * gv.z + bv2.z);
    pk[3] = f2b((v[j].w - mean) * rstd * gv.w + bv2.w);
    *(u16x4*)(orow + 4 * f) = pk;
  }
}

// ---------------- heads reduce: HP [4][512][1024] -> out [2][512][512]
__global__ __launch_bounds__(256)
void headred_k(const float* __restrict__ HP, float* __restrict__ out)
{
  int i4 = blockIdx.x * 256 + threadIdx.x;   // 131072 float4 groups
  int st = i4 >> 16, loc = i4 & 65535;
  int r = loc >> 7, c4 = loc & 127;
  const float4* basep = (const float4*)HP + (long)r * 256 + st * 128 + c4;
  float4 a = basep[0], b = basep[131072], c = basep[2 * 131072], d = basep[3 * 131072];
  float4 rr; rr.x = a.x + b.x + c.x + d.x; rr.y = a.y + b.y + c.y + d.y;
  rr.z = a.z + b.z + c.z + d.z; rr.w = a.w + b.w + c.w + d.w;
  ((float4*)out)[i4] = rr;
}

// ---------------- GEMM: C[M,N] = A[M,K](bf16) @ Bt[N,K](bf16)^T
// templated tile: BM x BN block, WM x WN per wave, BK=64, ring-2 LDS, XCD swizzle
#define EPI_PLAIN 0
#define EPI_PE    1
#define EPI_QKV   2
#define EPI_GELU  4
#define EPI_PART  5
#define EPI_HEAD  6

template<int BM, int BN, int WM, int WN, int EPI, bool BIAS>
__global__ __launch_bounds__(256)
void gemm_k(const u16* __restrict__ A, const u16* __restrict__ Bt, const float* __restrict__ bias,
            float* outf, u16* outb, u16* qb, u16* kb, u16* vT, const float* aux,
            int M, int N, int Ks, int lda, int ldb, int ldc,
            int astr, int aoff, int cstr, int coff, int pstr)
{
  constexpr int NWC = BN / WN;               // waves along N
  constexpr int NT  = (BM / WM) * NWC * 64;  // threads (=256 for all configs used)
  constexpr int LCH = (BM + BN) * 8;         // 16B chunks per buffer
  constexpr int LPT = LCH / NT;              // global_load_lds per thread per stage
  constexpr int MR = WM / 16, NR = WN / 16;
  __shared__ alignas(16) u16 Sl[2][(BM + BN) * 64];

  const int tid = threadIdx.x;
  // XCD swizzle: y-panel-major linearization, contiguous chunk per XCD
  const int gx = gridDim.x, gy = gridDim.y;
  const int nwg = gx * gy * gridDim.z;
  const int lin = (blockIdx.z * gy + blockIdx.y) * gx + blockIdx.x;
  const int wg = xcd_swz(lin, nwg);
  const int bx = wg % gx, t1g = wg / gx;
  const int by = t1g % gy, bz = t1g / gy;
  const int m0 = bx * BM, n0 = by * BN;
  const int koff = bz * Ks;
  const int lane = tid & 63, w = tid >> 6, l15 = lane & 15, g = lane >> 4;
  const int wr = w / NWC, wc = w % NWC;
  int aoffE = aoff;
  if constexpr (EPI == EPI_HEAD) aoffE += (by >= (int)(gy >> 1)) ? 256 : 0;

  // staging chunk c = tid + NT*j; chunk -> (region,row,slot); swizzled SOURCE, linear DEST
  const u16* gp[LPT]; int lbase[LPT];
  #pragma unroll
  for (int j = 0; j < LPT; ++j) {
    int c = tid + NT * j;
    int slot = c & 7;
    if (c < BM * 8) {
      int row = c >> 3;
      int se = (slot ^ (row & 7)) * 8;
      int am = m0 + row;
      gp[j] = A + (long)((am >> 8) * astr + aoffE + (am & 255)) * lda + koff + se;
    } else {
      int rb = c - BM * 8;
      int row = rb >> 3;
      int se = (slot ^ (row & 7)) * 8;
      gp[j] = Bt + (long)(n0 + row) * ldb + koff + se;
    }
    lbase[j] = w * 512 + NT * 8 * j;         // wave-uniform LDS base (u16 elems)
  }

  // ds_read byte offsets: [ks][frag]
  int offA[2][MR], offB[2][NR];
  #pragma unroll
  for (int ks = 0; ks < 2; ++ks) {
    int s = 4 * ks + g;
    #pragma unroll
    for (int mi = 0; mi < MR; ++mi) {
      int r = wr * WM + mi * 16 + l15;
      offA[ks][mi] = r * 128 + ((s ^ (r & 7)) << 4);
    }
    #pragma unroll
    for (int ni = 0; ni < NR; ++ni) {
      int r = wc * WN + ni * 16 + l15;
      offB[ks][ni] = BM * 128 + r * 128 + ((s ^ (r & 7)) << 4);
    }
  }

  f32x4 acc[MR][NR];
  #pragma unroll
  for (int mi = 0; mi < MR; ++mi)
  #pragma unroll
  for (int ni = 0; ni < NR; ++ni) acc[mi][ni] = f32x4{};

  auto STAGE = [&](int kt, int buf) {
    #pragma unroll
    for (int j = 0; j < LPT; ++j) GLOAD16(gp[j] + kt, &Sl[buf][lbase[j]]);
  };
  auto COMPUTE = [&](int buf) {
    const char* Sb = (const char*)&Sl[buf][0];
    #pragma unroll
    for (int ks = 0; ks < 2; ++ks) {
      bf16x8 a[MR], b[NR];
      #pragma unroll
      for (int mi = 0; mi < MR; ++mi) a[mi] = *(const bf16x8*)(Sb + offA[ks][mi]);
      #pragma unroll
      for (int ni = 0; ni < NR; ++ni) b[ni] = *(const bf16x8*)(Sb + offB[ks][ni]);
      #pragma unroll
      for (int mi = 0; mi < MR; ++mi)
      #pragma unroll
      for (int ni = 0; ni < NR; ++ni)
        acc[mi][ni] = __builtin_amdgcn_mfma_f32_16x16x32_bf16(a[mi], b[ni], acc[mi][ni], 0, 0, 0);
    }
  };

  const int nIter = Ks >> 6;
  STAGE(0, 0);
  if (nIter > 1) STAGE(64, 1);
  for (int t = 0; t < nIter; ++t) {
    if (t + 1 < nIter) {
      if constexpr (LPT == 8)      asm volatile("s_waitcnt vmcnt(8)" ::: "memory");
      else if constexpr (LPT == 6) asm volatile("s_waitcnt vmcnt(6)" ::: "memory");
      else                         asm volatile("s_waitcnt vmcnt(4)" ::: "memory");
    } else {
      asm volatile("s_waitcnt vmcnt(0)" ::: "memory");
    }
    __builtin_amdgcn_s_barrier();            // all waves' stage-t landed
    COMPUTE(t & 1);
    if (t + 2 < nIter) {
      __builtin_amdgcn_s_barrier();          // all waves done reading buf[t&1]
      STAGE((t + 2) << 6, t & 1);
    }
  }

  #pragma unroll
  for (int mi = 0; mi < MR; ++mi)
  #pragma unroll
  for (int ni = 0; ni < NR; ++ni) {
    f32x4 a = acc[mi][ni];
    int col = n0 + wc * WN + ni * 16 + l15;
    float bv = BIAS ? bias[col] : 0.0f;
    int mlb = m0 + wr * WM + mi * 16 + 4 * g;
    if (EPI == EPI_QKV) {
      if (col >= 1536) {
        int c2 = col - 1536, hh = c2 >> 6, dd = c2 & 63;
        int bb2 = mlb >= 768 ? 1 : 0;
        int t0 = mlb - bb2 * 768;
        u16x4 pk;
        #pragma unroll
        for (int r = 0; r < 4; ++r) pk[r] = f2b(a[r] + bv);
        *(u16x4*)(vT + (long)((bb2 * 12 + hh) * 64 + dd) * 768 + t0) = pk;
      } else {
        u16* dst = (col < 768) ? (qb + (long)mlb * 768 + col) : (kb + (long)mlb * 768 + (col - 768));
        #pragma unroll
        for (int r = 0; r < 4; ++r) dst[(long)r * 768] = f2b(a[r] + bv);
      }
    } else {
      #pragma unroll
      for (int r = 0; r < 4; ++r) {
        int rg = mlb + r;
        long crow = (long)(rg >> 8) * cstr + coff + (rg & 255);
        float v = a[r] + bv;
        if (EPI == EPI_PLAIN)      outf[crow * ldc + col] = v;
        else if (EPI == EPI_PE)    outf[crow * ldc + col] = v + aux[(long)(rg & 255) * 768 + col];
        else if (EPI == EPI_PART || EPI == EPI_HEAD)
                                   outf[(long)bz * pstr + (long)rg * ldc + col] = v;
        else if (EPI == EPI_GELU)  outb[crow * ldc + col] = f2b(0.5f * v * (1.0f + erff(v * 0.70710678f)));
      }
    }
  }
}

// ---------------- flash attention: 32 q-rows / 2 waves per WG, masked-tile skipping
#define MFMA_BF16 __builtin_amdgcn_mfma_f32_16x16x32_bf16
__global__ __launch_bounds__(128)
void attn_k(const u16* __restrict__ qb, const u16* __restrict__ kb,
            const u16* __restrict__ vT, u16* __restrict__ y)
{
  __shared__ alignas(16) u16 Kl[3 * 4096];
  __shared__ alignas(16) u16 Vl[3 * 4096];
  __shared__ alignas(16) u16 Pl[2][16 * 72];
  // XCD swizzle: bh-major linearization so same-bh blocks share an XCD's L2
  const int gx = gridDim.x, gy = gridDim.y;
  const int nwg = gx * gy;
  const int lin = blockIdx.y * gx + blockIdx.x;
  const int wg = xcd_swz(lin, nwg);
  const int qt = wg % gx, bh = wg / gx;
  const int b = bh / 12, h = bh - b * 12;
  const int tid = threadIdx.x, w = tid >> 6, lane = tid & 63, l15 = lane & 15, g = lane >> 4;
  const int qrow = qt * 32 + w * 16 + l15;
  const int qm = qrow & 255;
  const int q0 = (qt * 32) & 255;
  const unsigned nw4 = (q0 >> 6) + 1;
  const int niter = 3 * nw4;
  const u16* qp = qb + (long)(b * 768 + qrow) * 768 + h * 64;
  bf16x8 qf0 = *(const bf16x8*)(qp + 8 * g);
  bf16x8 qf1 = *(const bf16x8*)(qp + 32 + 8 * g);
  f32x4 O0{}, O1{}, O2{}, O3{};
  float m_run = -1e30f, l_run = 0.0f;

  const u16* kp[4]; const u16* vp[4]; int ldsb[4];
  #pragma unroll
  for (int j = 0; j < 4; ++j) {
    int i = tid + 128 * j;
    int r = i >> 3, sl = ((i & 7) ^ (r & 7)) * 8;
    kp[j] = kb + (long)(b * 768 + r) * 768 + h * 64 + sl;
    vp[j] = vT + (long)(bh * 64 + r) * 768 + sl;
    ldsb[j] = (w + 2 * j) * 512;
  }

  auto STAGE = [&](int kt, int q) {
    u16* kd = Kl + q * 4096; u16* vd = Vl + q * 4096;
    #pragma unroll
    for (int j = 0; j < 4; ++j) GLOAD16(kp[j] + (long)kt * 64 * 768, kd + ldsb[j]);
    #pragma unroll
    for (int j = 0; j < 4; ++j) GLOAD16(vp[j] + kt * 64, vd + ldsb[j]);
  };
  auto MAP = [&](int it) {
    unsigned sb = (unsigned)it / nw4;
    return (int)(sb * 4 + ((unsigned)it - sb * nw4));
  };

  STAGE(MAP(0), 0);
  STAGE(MAP(1), 1);
  int cur = 0;
  for (int it = 0; it < niter; ++it) {
    if (it < niter - 1) asm volatile("s_waitcnt vmcnt(8)" ::: "memory");
    else                asm volatile("s_waitcnt vmcnt(0)" ::: "memory");
    __builtin_amdgcn_s_barrier();
    if (it + 2 < niter) STAGE(MAP(it + 2), cur == 0 ? 2 : cur - 1);
    const int kt = MAP(it);
    const char* Kb = (const char*)Kl + cur * 8192;
    const char* Vb = (const char*)Vl + cur * 8192;

    f32x4 s0{}, s1{}, s2{}, s3{};
    #pragma unroll
    for (int ks = 0; ks < 2; ++ks) {
      bf16x8 qf = ks ? qf1 : qf0;
      int sb = ((4 * ks + g) ^ (l15 & 7)) << 4;
      bf16x8 k0 = *(const bf16x8*)(Kb + (0  + l15) * 128 + sb);
      bf16x8 k1 = *(const bf16x8*)(Kb + (16 + l15) * 128 + sb);
      bf16x8 k2 = *(const bf16x8*)(Kb + (32 + l15) * 128 + sb);
      bf16x8 k3 = *(const bf16x8*)(Kb + (48 + l15) * 128 + sb);
      s0 = MFMA_BF16(k0, qf, s0, 0, 0, 0);
      s1 = MFMA_BF16(k1, qf, s1, 0, 0, 0);
      s2 = MFMA_BF16(k2, qf, s2, 0, 0, 0);
      s3 = MFMA_BF16(k3, qf, s3, 0, 0, 0);
    }
    float sv[16]; float tm = -1e30f;
    #pragma unroll
    for (int mt = 0; mt < 4; ++mt) {
      f32x4 sm4 = (mt == 0) ? s0 : (mt == 1) ? s1 : (mt == 2) ? s2 : s3;
      #pragma unroll
      for (int r = 0; r < 4; ++r) {
        int kg = kt * 64 + mt * 16 + 4 * g + r;
        float val = ((kg & 255) <= qm) ? sm4[r] * 0.125f : -1e30f;
        sv[mt * 4 + r] = val; tm = fmaxf(tm, val);
      }
    }
    tm = fmaxf(tm, __shfl_xor(tm, 16));
    tm = fmaxf(tm, __shfl_xor(tm, 32));
    float mn = fmaxf(m_run, tm);
    float alpha = __expf(m_run - mn);
    float ps = 0.0f; u16 pb16[16];
    #pragma unroll
    for (int j = 0; j < 16; ++j) {
      float p = (sv[j] <= -1e29f) ? 0.0f : __expf(sv[j] - mn);
      ps += p; pb16[j] = f2b(p);
    }
    ps += __shfl_xor(ps, 16); ps += __shfl_xor(ps, 32);
    l_run = l_run * alpha + ps; m_run = mn;
    float a0 = __shfl(alpha, 4 * g + 0);
    float a1 = __shfl(alpha, 4 * g + 1);
    float a2 = __shfl(alpha, 4 * g + 2);
    float a3 = __shfl(alpha, 4 * g + 3);
    #pragma unroll
    for (int mt = 0; mt < 4; ++mt) {
      u16x4 pk; pk[0] = pb16[4*mt]; pk[1] = pb16[4*mt+1]; pk[2] = pb16[4*mt+2]; pk[3] = pb16[4*mt+3];
      *(u16x4*)((char*)&Pl[w][0] + l15 * 144 + mt * 32 + 8 * g) = pk;
    }
    O0[0] *= a0; O0[1] *= a1; O0[2] *= a2; O0[3] *= a3;
    O1[0] *= a0; O1[1] *= a1; O1[2] *= a2; O1[3] *= a3;
    O2[0] *= a0; O2[1] *= a1; O2[2] *= a2; O2[3] *= a3;
    O3[0] *= a0; O3[1] *= a1; O3[2] *= a2; O3[3] *= a3;
    asm volatile("s_waitcnt lgkmcnt(0)" ::: "memory");
    __builtin_amdgcn_sched_barrier(0);
    #pragma unroll
    for (int ks = 0; ks < 2; ++ks) {
      bf16x8 pf = *(const bf16x8*)((const char*)&Pl[w][0] + l15 * 144 + 64 * ks + 16 * g);
      int sb = ((4 * ks + g) ^ (l15 & 7)) << 4;
      bf16x8 v0 = *(const bf16x8*)(Vb + (0  + l15) * 128 + sb);
      bf16x8 v1 = *(const bf16x8*)(Vb + (16 + l15) * 128 + sb);
      bf16x8 v2 = *(const bf16x8*)(Vb + (32 + l15) * 128 + sb);
      bf16x8 v3 = *(const bf16x8*)(Vb + (48 + l15) * 128 + sb);
      O0 = MFMA_BF16(pf, v0, O0, 0, 0, 0);
      O1 = MFMA_BF16(pf, v1, O1, 0, 0, 0);
      O2 = MFMA_BF16(pf, v2, O2, 0, 0, 0);
      O3 = MFMA_BF16(pf, v3, O3, 0, 0, 0);
    }
    cur = (cur == 2) ? 0 : cur + 1;
  }
  float n0i = 1.0f / __shfl(l_run, 4 * g + 0);
  float n1i = 1.0f / __shfl(l_run, 4 * g + 1);
  float n2i = 1.0f / __shfl(l_run, 4 * g + 2);
  float n3i = 1.0f / __shfl(l_run, 4 * g + 3);
  long yr = (long)(b * 768 + qt * 32 + w * 16 + 4 * g);
  #pragma unroll
  for (int ni = 0; ni < 4; ++ni) {
    f32x4 Ov = (ni == 0) ? O0 : (ni == 1) ? O1 : (ni == 2) ? O2 : O3;
    int c = h * 64 + ni * 16 + l15;
    y[(yr + 0) * 768 + c] = f2b(Ov[0] * n0i);
    y[(yr + 1) * 768 + c] = f2b(Ov[1] * n1i);
    y[(yr + 2) * 768 + c] = f2b(Ov[2] * n2i);
    y[(yr + 3) * 768 + c] = f2b(Ov[3] * n3i);
  }
}

// ================= host =================
extern "C" void kernel_launch(void* const* d_in, const int* in_sizes, int n_in,
                              void* d_out, int out_size, void* d_ws, size_t ws_size,
                              hipStream_t stream)
{
  (void)in_sizes; (void)n_in; (void)out_size;
  auto F = [&](int i){ return (const float*)d_in[i]; };
  const int* idx_up = (const int*)d_in[0];
  const int* idx_dn = (const int*)d_in[1];
  const float* cond = F(2);
  const float* teu = F(3);
  const float* ted = F(4);
  const float* pe  = F(5);
  const float* cw  = F(6);
  const float* cb  = F(7);
  float* outp = (float*)d_out;
  char* ws = (char*)d_ws;

  size_t o = 0;
  auto take = [&](size_t bytes){ void* p = ws + o; o += bytes; return p; };
  float* x    = (float*)take(4718592);   // [1536][768] f32 residual stream
  u16*   h    = (u16*)take(2359296);     // LN out bf16
  u16*   qbuf = (u16*)take(2359296);
  u16*   kbuf = (u16*)take(2359296);
  u16*   vT   = (u16*)take(2359296);     // [24][64][768]
  u16*   y    = (u16*)take(2359296);
  u16*   fca  = (u16*)take(9437184);     // [1536][3072]
  u16*   xf   = (u16*)take(2359296);
  u16*   cbf  = (u16*)take(458752);      // cond bf16 [512][448]
  float* qkvb = (float*)take(110592);    // [12][2304]
  u16*   hutd = (u16*)take(1572864);     // [1024][768] (up rows 0-511, down 512-1023)
  u16*   cwt  = (u16*)take(688128);      // [768][448]
  float* P1   = (float*)take(9437184);   // proj partials  [2][1536][768]
  float* P2   = (float*)take(9437184);   // proj2 partials [2][1536][768]
  float* HP   = (float*)take(8388608);   // head partials  [4][512][1024]
  const size_t WL = 14155776;            // per-layer transposed weights (bytes)
  bool up = (ws_size >= o + 12 * WL);
  size_t nsl = up ? 12 : 1;
  u16* qkvt = (u16*)(ws + o);
  u16* wot  = qkvt + nsl * 2304 * 768;
  u16* fct  = wot  + nsl * 768 * 768;
  u16* prt  = fct  + nsl * 3072 * 768;

  auto trans = [&](const float* src, u16* dst, int K, int N, int Kp, long sIn, long sOut, int nz){
    transw_k<<<dim3(N / 32, Kp / 32, nz), dim3(256), 0, stream>>>(src, dst, K, N, Kp, sIn, sOut);
  };

  if (up) {
    for (int s = 0; s < 2; ++s) {
      for (int p = 0; p < 3; ++p)
        trans(F(8 + 16*s + 2 + 2*p), qkvt + (size_t)s*6*2304*768 + (size_t)p*768*768,
              768, 768, 768, 768L*768, 2304L*768, 6);
      trans(F(8 + 16*s + 8),  wot + (size_t)s*6*768*768,  768, 768, 768, 768L*768, 768L*768, 6);
      trans(F(8 + 16*s + 12), fct + (size_t)s*6*3072*768, 768, 3072, 768, 768L*3072, 3072L*768, 6);
      trans(F(8 + 16*s + 14), prt + (size_t)s*6*768*3072, 3072, 768, 3072, 3072L*768, 768L*3072, 6);
    }
  }
  trans(F(42), hutd, 768, 512, 768, 0, 0, 1);
  trans(F(43), hutd + 512 * 768, 768, 512, 768, 0, 0, 1);
  trans(cw,    cwt, 438, 768, 448, 0, 0, 1);
  biascat_k<<<dim3(108), dim3(256), 0, stream>>>(F(11), F(13), F(15), F(27), F(29), F(31), qkvb);
  condcvt_k<<<dim3(896), dim3(256), 0, stream>>>(cond, cbf);
  embed_k<<<dim3(768), dim3(256), 0, stream>>>(idx_up, idx_dn, teu, ted, pe, x);
  // cond @ cond_w + cond_b + pos_emb -> x rows b*768 + (0..255)
  gemm_k<64, 64, 32, 32, EPI_PE, true><<<dim3(8, 12, 1), dim3(256), 0, stream>>>(cbf, cwt, cb,
      x, nullptr, nullptr, nullptr, nullptr, pe,
      512, 768, 448, 448, 448, 768, 256, 0, 768, 0, 0);

  for (int l = 0; l < 12; ++l) {
    int s = l / 6, li = l % 6;
    u16* qkvt_l = qkvt + (up ? (size_t)l : 0) * 2304 * 768;
    u16* wot_l  = wot  + (up ? (size_t)l : 0) * 768 * 768;
    u16* fct_l  = fct  + (up ? (size_t)l : 0) * 3072 * 768;
    u16* prt_l  = prt  + (up ? (size_t)l : 0) * 768 * 3072;
    if (!up) {
      for (int p = 0; p < 3; ++p)
        trans(F(8 + 16*s + 2 + 2*p) + (size_t)li*768*768, qkvt_l + (size_t)p*768*768, 768, 768, 768, 0, 0, 1);
      trans(F(8 + 16*s + 8)  + (size_t)li*768*768,  wot_l, 768, 768, 768, 0, 0, 1);
      trans(F(8 + 16*s + 12) + (size_t)li*768*3072, fct_l, 768, 3072, 768, 0, 0, 1);
      trans(F(8 + 16*s + 14) + (size_t)li*3072*768, prt_l, 3072, 768, 3072, 0, 0, 1);
    }
    // LN1 (fused with previous layer's proj2 split-K reduce + residual)
    if (l == 0) {
      lnred_k<0, false><<<dim3(384), dim3(256), 0, stream>>>(x, nullptr, nullptr,
          F(8+16*s+0) + (size_t)li*768, F(8+16*s+1) + (size_t)li*768, nullptr, h);
    } else {
      int ps = (l - 1) / 6, pli = (l - 1) % 6;
      lnred_k<2, true><<<dim3(384), dim3(256), 0, stream>>>(x, P2,
          F(8+16*ps+15) + (size_t)pli*768,
          F(8+16*s+0) + (size_t)li*768, F(8+16*s+1) + (size_t)li*768, x, h);
    }
    gemm_k<128, 64, 32, 64, EPI_QKV, true><<<dim3(12, 36, 1), dim3(256), 0, stream>>>(h, qkvt_l, qkvb + (size_t)l*2304,
        nullptr, nullptr, qbuf, kbuf, vT, nullptr,
        1536, 2304, 768, 768, 768, 768, 256, 0, 256, 0, 0);
    attn_k<<<dim3(24, 24), dim3(128), 0, stream>>>(qbuf, kbuf, vT, y);
    // attn out proj: split-K x2 -> P1
    gemm_k<128, 64, 32, 64, EPI_PART, false><<<dim3(12, 12, 2), dim3(256), 0, stream>>>(y, wot_l, nullptr,
        P1, nullptr, nullptr, nullptr, nullptr, nullptr,
        1536, 768, 384, 768, 768, 768, 256, 0, 256, 0, 1179648);
    // LN2 fused with proj reduce + residual + bo
    lnred_k<2, true><<<dim3(384), dim3(256), 0, stream>>>(x, P1,
        F(8+16*s+9) + (size_t)li*768,
        F(8+16*s+10) + (size_t)li*768, F(8+16*s+11) + (size_t)li*768, x, h);
    gemm_k<128, 64, 32, 64, EPI_GELU, true><<<dim3(12, 48, 1), dim3(256), 0, stream>>>(h, fct_l, F(8+16*s+13) + (size_t)li*3072,
        nullptr, fca, nullptr, nullptr, nullptr, nullptr,
        1536, 3072, 768, 768, 768, 3072, 256, 0, 256, 0, 0);
    // MLP out proj: split-K x2 -> P2 (reduced by next lnred / ln_f)
    gemm_k<128, 64, 32, 64, EPI_PART, false><<<dim3(12, 12, 2), dim3(256), 0, stream>>>(fca, prt_l, nullptr,
        P2, nullptr, nullptr, nullptr, nullptr, nullptr,
        1536, 768, 1536, 3072, 3072, 768, 256, 0, 256, 0, 1179648);
  }
  // ln_f fused with last proj2 reduce (x not needed afterwards)
  lnred_k<2, false><<<dim3(384), dim3(256), 0, stream>>>(x, P2,
      F(8+16*1+15) + (size_t)5*768, F(40), F(41), nullptr, xf);
  // heads: one merged GEMM (N=1024 over both heads), split-K x4, then fused reduce
  gemm_k<64, 64, 32, 32, EPI_HEAD, false><<<dim3(8, 16, 4), dim3(256), 0, stream>>>(xf, hutd, nullptr,
      HP, nullptr, nullptr, nullptr, nullptr, nullptr,
      512, 1024, 192, 768, 768, 1024, 768, 256, 256, 0, 524288);
  headred_k<<<dim3(512), dim3(256), 0, stream>>>(HP, outp);
}